// Round 2
// baseline (9653.412 us; speedup 1.0000x reference)
//
#include <hip/hip_runtime.h>
#include <hip/hip_bf16.h>

typedef __attribute__((ext_vector_type(8))) short short8v;
typedef __attribute__((ext_vector_type(4))) float f32x4;
typedef __attribute__((ext_vector_type(4))) float float4v;

#define DEV __device__ __forceinline__

DEV short f2bfs(float x){
  union { float f; unsigned u; } v; v.f = x;
  unsigned r = (v.u + 0x7FFFu + ((v.u >> 16) & 1u)) >> 16;
  return (short)(unsigned short)r;
}
DEV float bfs2f(short s){
  union { unsigned u; float f; } v; v.u = ((unsigned)(unsigned short)s) << 16;
  return v.f;
}
DEV float sigm(float x){ return 1.f / (1.f + __expf(-x)); }
// glu-pair interleave map: z-col j (0..2047) -> row n' so a-col and gate-col land
// 16 apart inside one wave's 32-col strip.
DEV int zmap(int j){ int g = (j >= 1024) ? 1 : 0; int i = j - (g << 10); return (i & 15) + ((i >> 4) << 5) + (g << 4); }

// ================= device-scope grid barrier (8-way arrival + gen flag) =================
// bar[ i*16 ] i=0..7 : arrival counters (separate 64B lines); bar[128]: generation.
DEV void gbar(unsigned* bar, int nb){
  __syncthreads();
  if (threadIdx.x == 0){
    __builtin_amdgcn_fence(__ATOMIC_RELEASE, "agent");
    unsigned* gen = bar + 128;
    unsigned g = __hip_atomic_load(gen, __ATOMIC_RELAXED, __HIP_MEMORY_SCOPE_AGENT);
    int lane = blockIdx.x & 7;
    __hip_atomic_fetch_add(bar + lane*16, 1u, __ATOMIC_RELAXED, __HIP_MEMORY_SCOPE_AGENT);
    if (blockIdx.x == 0){
      unsigned sum;
      do {
        sum = 0;
#pragma unroll
        for (int i = 0; i < 8; i++) sum += __hip_atomic_load(bar + i*16, __ATOMIC_RELAXED, __HIP_MEMORY_SCOPE_AGENT);
      } while (sum < (unsigned)nb);
#pragma unroll
      for (int i = 0; i < 8; i++) __hip_atomic_store(bar + i*16, 0u, __ATOMIC_RELAXED, __HIP_MEMORY_SCOPE_AGENT);
      __hip_atomic_store(gen, g + 1u, __ATOMIC_RELEASE, __HIP_MEMORY_SCOPE_AGENT);
    } else {
      while (__hip_atomic_load(gen, __ATOMIC_RELAXED, __HIP_MEMORY_SCOPE_AGENT) == g)
        __builtin_amdgcn_s_sleep(1);
    }
    __builtin_amdgcn_fence(__ATOMIC_ACQUIRE, "agent");
  }
  __syncthreads();
  __builtin_amdgcn_fence(__ATOMIC_ACQUIRE, "agent");
}

// ================= persistent-kernel tick phases =================

// Phase 1: fused Qh projection + cross-attention. unit u -> (h = u&7, b = u>>3)
DEV void phase_qhcross(int u, const short* __restrict__ Wfq, const float* __restrict__ bfq,
    const short* __restrict__ Kc, const short* __restrict__ Vc, const short* __restrict__ S_bf,
    short* __restrict__ oa_bf, float* __restrict__ stats, float* smf, int tid, int zero_stats)
{
  float* Srow = smf;          // 1024
  float* qs   = smf + 1024;   // 64
  float* wsm  = smf + 1088;   // 256
  float* red  = smf + 1344;   // 256
  int h = u & 7, b = u >> 3;
  __syncthreads();
  const short* sp = S_bf + b*1024;
#pragma unroll
  for (int r = 0; r < 4; r++){ int idx = tid + r*256; Srow[idx] = bfs2f(sp[idx]); }
  if (zero_stats && tid < 128) stats[tid] = 0.f;
  __syncthreads();
  {
    int d = tid & 63, c = tid >> 6;
    const short* wp = Wfq + (size_t)(h*64 + d)*1024 + c*256;
    const float* srp = Srow + c*256;
    float acc = 0.f;
#pragma unroll 4
    for (int i = 0; i < 256; i += 8){
      short8v wv = *(const short8v*)(wp + i);
#pragma unroll
      for (int j = 0; j < 8; j++) acc += bfs2f(wv[j]) * srp[i + j];
    }
    red[tid] = acc;
  }
  __syncthreads();
  if (tid < 64) qs[tid] = bfq[h*64 + tid] + red[tid] + red[tid+64] + red[tid+128] + red[tid+192];
  __syncthreads();
  // cross-attention
  float sv = -1e30f;
  if (tid < 196){
    const short* kp = Kc + ((size_t)(b*196 + tid)*512 + h*64);
    float acc = 0.f;
#pragma unroll
    for (int j = 0; j < 64; j += 8){
      short8v kv8 = *(const short8v*)(kp + j);
#pragma unroll
      for (int u8 = 0; u8 < 8; u8++) acc += bfs2f(kv8[u8]) * qs[j + u8];
    }
    sv = acc * 0.125f;
  }
  red[tid] = sv; __syncthreads();
  for (int s = 128; s > 0; s >>= 1){ if (tid < s) red[tid] = fmaxf(red[tid], red[tid+s]); __syncthreads(); }
  float M = red[0]; __syncthreads();
  float e = (tid < 196) ? __expf(sv - M) : 0.f;
  wsm[tid] = e; red[tid] = e; __syncthreads();
  for (int s = 128; s > 0; s >>= 1){ if (tid < s) red[tid] += red[tid+s]; __syncthreads(); }
  float Z = red[0]; __syncthreads();
  int dd = tid & 63, cc = tid >> 6;
  float acc = 0.f;
  for (int s = cc; s < 196; s += 4) acc += wsm[s] * bfs2f(Vc[(size_t)(b*196 + s)*512 + h*64 + dd]);
  red[tid] = acc; __syncthreads();
  if (tid < 64){
    float o = (red[tid] + red[tid+64] + red[tid+128] + red[tid+192]) / Z;
    oa_bf[(size_t)b*1536 + h*64 + tid] = f2bfs(o);
  }
  __syncthreads();
}

// Phase 2: GLU GEMM, 64 units (32-col strips of N=2048), 4-wave K-split over K=1536.
DEV void phase_glu(int u, const short* __restrict__ Wz, const float* __restrict__ bz,
    const short* __restrict__ oa_bf, float* __restrict__ ubuf, float* __restrict__ stats,
    float* smf, int tid)
{
  float* part   = smf;        // 4*64*32 = 8192
  float* statsl = smf + 8192; // 128
  int n0 = u * 32;
  __syncthreads();
  if (tid < 128) statsl[tid] = 0.f;
  int w = tid >> 6, l15 = tid & 15, l4 = (tid >> 4) & 3;
  f32x4 acc[4][2];
#pragma unroll
  for (int mi = 0; mi < 4; mi++)
#pragma unroll
    for (int ni = 0; ni < 2; ni++) acc[mi][ni] = (f32x4){0.f,0.f,0.f,0.f};
#pragma unroll 2
  for (int it = 0; it < 12; it++){
    int ks = w*384 + it*32 + l4*8;
    short8v a4[4], bb[2];
#pragma unroll
    for (int mi = 0; mi < 4; mi++)
      a4[mi] = *(const short8v*)(oa_bf + (size_t)(mi*16 + l15)*1536 + ks);
#pragma unroll
    for (int ni = 0; ni < 2; ni++)
      bb[ni] = *(const short8v*)(Wz + (size_t)(n0 + ni*16 + l15)*1536 + ks);
#pragma unroll
    for (int mi = 0; mi < 4; mi++)
#pragma unroll
      for (int ni = 0; ni < 2; ni++)
        acc[mi][ni] = __builtin_amdgcn_mfma_f32_16x16x32_bf16(a4[mi], bb[ni], acc[mi][ni], 0, 0, 0);
  }
#pragma unroll
  for (int mi = 0; mi < 4; mi++)
#pragma unroll
    for (int ni = 0; ni < 2; ni++)
#pragma unroll
      for (int r = 0; r < 4; r++)
        part[w*2048 + (mi*16 + l4*4 + r)*32 + ni*16 + l15] = acc[mi][ni][r];
  __syncthreads();
  int m = tid >> 2;
  float s1 = 0.f, s2 = 0.f;
#pragma unroll
  for (int e = 0; e < 4; e++){
    int j = ((tid & 3) << 2) + e;
    float a = part[m*32 + j] + part[2048 + m*32 + j] + part[4096 + m*32 + j] + part[6144 + m*32 + j] + bz[n0 + j];
    float g = part[m*32 + 16 + j] + part[2048 + m*32 + 16 + j] + part[4096 + m*32 + 16 + j] + part[6144 + m*32 + 16 + j] + bz[n0 + 16 + j];
    float uv = a * sigm(g);
    ubuf[(size_t)m*1024 + (n0 >> 1) + j] = uv;
    s1 += uv; s2 += uv*uv;
  }
  atomicAdd(&statsl[m], s1); atomicAdd(&statsl[64 + m], s2);
  __syncthreads();
  if (tid < 64){ atomicAdd(&stats[tid], statsl[tid]); atomicAdd(&stats[64 + tid], statsl[64 + tid]); }
  __syncthreads();
}

// Phase 3: LN + trace append + per-neuron NLM. 512 units.
DEV void phase_nlm(int u, const float* __restrict__ ubuf, const float* __restrict__ stats,
    const float* __restrict__ g_s, const float* __restrict__ g_b, float* __restrict__ st,
    const float* __restrict__ w1, const float* __restrict__ b1,
    const float* __restrict__ w2, const float* __restrict__ b2,
    short* __restrict__ oa_bf, int t, float* smf, int tid)
{
  float* pl = smf; // [2][8][16][16] = 4096
  int x = u & 63, y = u >> 6;
  int d_i = tid & 15, b_i = (tid >> 4) & 7, half = tid >> 7;
  int d = x*16 + d_i, b = y*8 + b_i;
  float mu = stats[b] * (1.f/1024.f);
  float var = stats[64 + b] * (1.f/1024.f) - mu*mu;
  float rs = rsqrtf(var + 1e-5f);
  float uv = ubuf[b*1024 + d];
  float state = (uv - mu)*rs*g_s[d] + g_b[d];
  int slot = t % 25;
  if (half == 0) st[(size_t)slot*65536 + b*1024 + d] = state;
  float pre[16];
#pragma unroll
  for (int hh = 0; hh < 16; hh++) pre[hh] = b1[d*32 + half*16 + hh];
  int p0 = (t + 1) % 25;
#pragma unroll 5
  for (int m = 0; m < 25; m++){
    int p = p0 + m; if (p >= 25) p -= 25;
    float sm = (p == slot) ? state : st[(size_t)p*65536 + b*1024 + d];
#pragma unroll
    for (int hh = 0; hh < 16; hh++) pre[hh] += sm * w1[(size_t)(m*32 + half*16 + hh)*1024 + d];
  }
  __syncthreads();
#pragma unroll
  for (int hh = 0; hh < 16; hh++) pl[((half*8 + b_i)*16 + hh)*16 + d_i] = pre[hh];
  __syncthreads();
  if (half == 0){
    float p2a = b2[d*2 + 0], p2g = b2[d*2 + 1];
#pragma unroll
    for (int i = 0; i < 16; i++){
      float hv = pl[((b_i)*16 + i)*16 + d_i] * sigm(pl[((8 + b_i)*16 + i)*16 + d_i]);
      p2a += hv * w2[(size_t)(i*2 + 0)*1024 + d];
      p2g += hv * w2[(size_t)(i*2 + 1)*1024 + d];
    }
    float act = p2a * sigm(p2g);
    oa_bf[(size_t)b*1536 + 512 + d] = f2bfs(act);
  }
  __syncthreads();
}

// Phase 4: QKV GEMM, 96 units (32-col strips of N=3072), 4-wave K-split over K=1024.
DEV void phase_qkv(int u, const short* __restrict__ Wqkv, const short* __restrict__ act_bf,
    short* __restrict__ Qb, short* __restrict__ Kb, float* __restrict__ vc, int slot,
    float* smf, int tid)
{
  float* part = smf; // 8192
  int n0 = u * 32;
  __syncthreads();
  int w = tid >> 6, l15 = tid & 15, l4 = (tid >> 4) & 3;
  f32x4 acc[4][2];
#pragma unroll
  for (int mi = 0; mi < 4; mi++)
#pragma unroll
    for (int ni = 0; ni < 2; ni++) acc[mi][ni] = (f32x4){0.f,0.f,0.f,0.f};
#pragma unroll 2
  for (int it = 0; it < 8; it++){
    int ks = w*256 + it*32 + l4*8;
    short8v a4[4], bb[2];
#pragma unroll
    for (int mi = 0; mi < 4; mi++)
      a4[mi] = *(const short8v*)(act_bf + (size_t)(mi*16 + l15)*1536 + ks);
#pragma unroll
    for (int ni = 0; ni < 2; ni++)
      bb[ni] = *(const short8v*)(Wqkv + (size_t)(n0 + ni*16 + l15)*1024 + ks);
#pragma unroll
    for (int mi = 0; mi < 4; mi++)
#pragma unroll
      for (int ni = 0; ni < 2; ni++)
        acc[mi][ni] = __builtin_amdgcn_mfma_f32_16x16x32_bf16(a4[mi], bb[ni], acc[mi][ni], 0, 0, 0);
  }
#pragma unroll
  for (int mi = 0; mi < 4; mi++)
#pragma unroll
    for (int ni = 0; ni < 2; ni++)
#pragma unroll
      for (int r = 0; r < 4; r++)
        part[w*2048 + (mi*16 + l4*4 + r)*32 + ni*16 + l15] = acc[mi][ni][r];
  __syncthreads();
  int m = tid >> 2;
#pragma unroll
  for (int e = 0; e < 8; e++){
    int nl = ((tid & 3) << 3) + e;
    float v = part[m*32 + nl] + part[2048 + m*32 + nl] + part[4096 + m*32 + nl] + part[6144 + m*32 + nl];
    int n = n0 + nl;
    if (n < 1024)      Qb[((size_t)m*1024 + n)*32 + slot] = f2bfs(v);
    else if (n < 2048) Kb[((size_t)m*1024 + (n-1024))*32 + slot] = f2bfs(v);
    else               vc[(size_t)m*1024 + (n-2048)] = v;
  }
  __syncthreads();
}

// Phase 5: neuron-sync attention. unit u -> (h = u&7, b = u>>3)
DEV void phase_sync(int u, int t, const short* __restrict__ Qbuf, const short* __restrict__ Kbuf,
    const float* __restrict__ vcur, float* __restrict__ S, short* __restrict__ S_bf,
    short* __restrict__ SyncO, float* smf, int tid)
{
  short8v* qlds = (short8v*)smf;
  short8v* klds = ((short8v*)smf) + 512;
  int h = u & 7, b = u >> 3;
  __syncthreads();
  const short* qg = Qbuf + ((size_t)b*1024 + h*128)*32;
  const short* kg = Kbuf + ((size_t)b*1024 + h*128)*32;
#pragma unroll
  for (int it = 0; it < 2; it++){
    int ch = tid + 256*it;
    int d = ch >> 2, c = ch & 3;
    int cs = c ^ ((d >> 1) & 3);
    qlds[d*4 + cs] = *(const short8v*)(qg + d*32 + c*8);
    klds[d*4 + cs] = *(const short8v*)(kg + d*32 + c*8);
  }
  __syncthreads();
  int w = tid >> 6, l15 = tid & 15, l4 = (tid >> 4) & 3;
  short8v af[2], bfr[8];
#pragma unroll
  for (int mi2 = 0; mi2 < 2; mi2++){
    int d = (2*w + mi2)*16 + l15;
    af[mi2] = qlds[d*4 + (l4 ^ ((d >> 1) & 3))];
  }
#pragma unroll
  for (int ni = 0; ni < 8; ni++){
    int e = ni*16 + l15;
    bfr[ni] = klds[e*4 + (l4 ^ ((e >> 1) & 3))];
  }
  f32x4 acc[2][8];
#pragma unroll
  for (int mi2 = 0; mi2 < 2; mi2++)
#pragma unroll
    for (int ni = 0; ni < 8; ni++)
      acc[mi2][ni] = (f32x4){0.f,0.f,0.f,0.f};
#pragma unroll
  for (int mi2 = 0; mi2 < 2; mi2++)
#pragma unroll
    for (int ni = 0; ni < 8; ni++)
      acc[mi2][ni] = __builtin_amdgcn_mfma_f32_16x16x32_bf16(af[mi2], bfr[ni], acc[mi2][ni], 0, 0, 0);
  float Vv[8];
#pragma unroll
  for (int ni = 0; ni < 8; ni++) Vv[ni] = vcur[b*1024 + h*128 + ni*16 + l15];
  const float scale = 0.08838834764831845f; // 1/sqrt(128)
#pragma unroll
  for (int mi2 = 0; mi2 < 2; mi2++)
#pragma unroll
    for (int r = 0; r < 4; r++){
      float sv[8]; float mx = -1e30f;
#pragma unroll
      for (int ni = 0; ni < 8; ni++){ sv[ni] = acc[mi2][ni][r]*scale; mx = fmaxf(mx, sv[ni]); }
#pragma unroll
      for (int off = 1; off < 16; off <<= 1) mx = fmaxf(mx, __shfl_xor(mx, off));
      float den = 0.f, num = 0.f;
#pragma unroll
      for (int ni = 0; ni < 8; ni++){ float p = __expf(sv[ni] - mx); den += p; num += p*Vv[ni]; }
#pragma unroll
      for (int off = 1; off < 16; off <<= 1){ den += __shfl_xor(den, off); num += __shfl_xor(num, off); }
      if (l15 == 0){
        int d = (2*w + mi2)*16 + l4*4 + r;
        float att = num / den;
        int oi = b*1024 + d*8 + h;
        S[oi] = att;
        S_bf[oi] = f2bfs(att);
        if (t >= 0) SyncO[((size_t)b*50 + t)*1024 + d*8 + h] = f2bfs(att);
      }
    }
  __syncthreads();
}

// ================= the persistent 50-tick kernel =================
__global__ __launch_bounds__(256, 2) void tick_all_k(
    const short* __restrict__ Wfq, const float* __restrict__ bfq,
    const short* __restrict__ Kc, const short* __restrict__ Vc,
    const short* __restrict__ Wz, const float* __restrict__ bz,
    float* __restrict__ ubuf, float* __restrict__ stats,
    const float* __restrict__ g_s, const float* __restrict__ g_b,
    float* __restrict__ st,
    const float* __restrict__ w1, const float* __restrict__ b1,
    const float* __restrict__ w2, const float* __restrict__ b2,
    const short* __restrict__ Wqkv,
    short* __restrict__ Qbuf, short* __restrict__ Kbuf, float* __restrict__ vcur,
    float* __restrict__ S, short* __restrict__ S_bf, short* __restrict__ SyncO,
    short* __restrict__ oa_bf, unsigned* bar)
{
  __shared__ float smf[8320]; // 33.3 KB: max overlay (phase2/4 partials)
  const int tid = threadIdx.x;
  const int bid = blockIdx.x;
  const int nb  = gridDim.x;

  // initial synchronisation (t = -1): S_bf <- sync_attn(hist0, act0)
  for (int u = bid; u < 512; u += nb) phase_sync(u, -1, Qbuf, Kbuf, vcur, S, S_bf, SyncO, smf, tid);
  gbar(bar, nb);

#pragma unroll 1
  for (int t = 0; t < 50; t++){
    for (int u = bid; u < 512; u += nb)
      phase_qhcross(u, Wfq, bfq, Kc, Vc, S_bf, oa_bf, stats, smf, tid, u == 0);
    gbar(bar, nb);
    for (int u = bid; u < 64; u += nb)
      phase_glu(u, Wz, bz, oa_bf, ubuf, stats, smf, tid);
    gbar(bar, nb);
    for (int u = bid; u < 512; u += nb)
      phase_nlm(u, ubuf, stats, g_s, g_b, st, w1, b1, w2, b2, oa_bf, t, smf, tid);
    gbar(bar, nb);
    for (int u = bid; u < 96; u += nb)
      phase_qkv(u, Wqkv, oa_bf + 512, Qbuf, Kbuf, vcur, t % 25, smf, tid);
    gbar(bar, nb);
    for (int u = bid; u < 512; u += nb)
      phase_sync(u, t, Qbuf, Kbuf, vcur, S, S_bf, SyncO, smf, tid);
    gbar(bar, nb);
  }
}

// ================= prologue / epilogue kernels (unchanged math) =================
struct EpiBF16 {
  short* C; int ldc; int domap;
  DEV void op(const f32x4 (&acc)[4][2], int m0, int n0, int l15, int l4, const float* bias) const {
#pragma unroll
    for (int mi = 0; mi < 4; mi++)
#pragma unroll
      for (int ni = 0; ni < 2; ni++){
        int n = n0 + ni*16 + l15;
        float bb = bias ? bias[n] : 0.f;
#pragma unroll
        for (int r = 0; r < 4; r++){
          int m = m0 + mi*16 + l4*4 + r;
          int mr = domap ? zmap(m) : m;
          C[(size_t)mr*ldc + n] = f2bfs(acc[mi][ni][r] + bb);
        }
      }
  }
};

struct EpiPred { // m = b*50+t ; out[b][n][t]
  float* outp;
  DEV void op(const f32x4 (&acc)[4][2], int m0, int n0, int l15, int l4, const float* bias) const {
#pragma unroll
    for (int mi = 0; mi < 4; mi++)
#pragma unroll
      for (int ni = 0; ni < 2; ni++){
        int n = n0 + ni*16 + l15;
        if (n >= 1000) continue;
        float bb = bias[n];
#pragma unroll
        for (int r = 0; r < 4; r++){
          int m = m0 + mi*16 + l4*4 + r;
          int b = m / 50, tt = m - b*50;
          outp[(size_t)b*50000 + (size_t)n*50 + tt] = acc[mi][ni][r] + bb;
        }
      }
  }
};

struct EpiKVpre { // bf16 store + per-row LN stats
  short* C; float* stats;
  DEV void op(const f32x4 (&acc)[4][2], int m0, int n0, int l15, int l4, const float* bias) const {
    float b0 = bias[n0 + l15], b1 = bias[n0 + 16 + l15];
#pragma unroll
    for (int mi = 0; mi < 4; mi++)
#pragma unroll
      for (int r = 0; r < 4; r++){
        int m = m0 + mi*16 + l4*4 + r;
        float v0 = acc[mi][0][r] + b0;
        float v1 = acc[mi][1][r] + b1;
        C[(size_t)m*512 + n0 + l15]      = f2bfs(v0);
        C[(size_t)m*512 + n0 + 16 + l15] = f2bfs(v1);
        float s = v0 + v1, s2 = v0*v0 + v1*v1;
#pragma unroll
        for (int off = 1; off < 16; off <<= 1){ s += __shfl_xor(s, off); s2 += __shfl_xor(s2, off); }
        if (l15 == 0){ atomicAdd(&stats[m*2], s); atomicAdd(&stats[m*2 + 1], s2); }
      }
  }
};

template<bool ABF16, typename EPI>
__global__ __launch_bounds__(256) void gemm_tn(const void* __restrict__ Aptr, int lda,
    const short* __restrict__ Bw, int ldb, const float* __restrict__ bias,
    int K, EPI epi)
{
  int tid = threadIdx.x;
  const int w = tid >> 6, l15 = tid & 15, l4 = (tid >> 4) & 3;
  const int m0 = blockIdx.y * 64;
  const int n0 = blockIdx.x * 128 + w * 32;
  f32x4 acc[4][2];
#pragma unroll
  for (int mi = 0; mi < 4; mi++)
#pragma unroll
    for (int ni = 0; ni < 2; ni++)
      acc[mi][ni] = (f32x4){0.f, 0.f, 0.f, 0.f};
#pragma unroll 4
  for (int kk = 0; kk < K; kk += 32){
    const int ks = kk + l4*8;
    short8v a[4], bfr[2];
#pragma unroll
    for (int mi = 0; mi < 4; mi++){
      const size_t row = (size_t)(m0 + mi*16 + l15);
      if (ABF16){
        a[mi] = *(const short8v*)((const short*)Aptr + row*lda + ks);
      } else {
        const float* ap = (const float*)Aptr + row*lda + ks;
        float4v f0 = *(const float4v*)ap;
        float4v f1 = *(const float4v*)(ap + 4);
        short8v tt;
        tt[0]=f2bfs(f0[0]); tt[1]=f2bfs(f0[1]); tt[2]=f2bfs(f0[2]); tt[3]=f2bfs(f0[3]);
        tt[4]=f2bfs(f1[0]); tt[5]=f2bfs(f1[1]); tt[6]=f2bfs(f1[2]); tt[7]=f2bfs(f1[3]);
        a[mi] = tt;
      }
    }
#pragma unroll
    for (int ni = 0; ni < 2; ni++)
      bfr[ni] = *(const short8v*)(Bw + (size_t)(n0 + ni*16 + l15)*ldb + ks);
#pragma unroll
    for (int mi = 0; mi < 4; mi++)
#pragma unroll
      for (int ni = 0; ni < 2; ni++)
        acc[mi][ni] = __builtin_amdgcn_mfma_f32_16x16x32_bf16(a[mi], bfr[ni], acc[mi][ni], 0, 0, 0);
  }
  epi.op(acc, m0, n0, l15, l4, bias);
}

__global__ __launch_bounds__(256) void vecmat_k(const float* __restrict__ W, int ldw,
    const float* __restrict__ v, const float* __restrict__ add, float* __restrict__ out, int K, int domap)
{
  int w = threadIdx.x >> 6, l = threadIdx.x & 63;
  int n = blockIdx.x*4 + w;
  float s = 0.f;
  for (int k = l; k < K; k += 64) s += W[(size_t)n*ldw + k]*v[k];
#pragma unroll
  for (int off = 32; off; off >>= 1) s += __shfl_xor(s, off);
  if (l == 0){ float o = s + (add ? add[n] : 0.f); out[domap ? zmap(n) : n] = o; }
}

__global__ void castW_k(short* dst, int dld, int drow0, int dcol0,
    const float* src, int sld, int N, int K, int transp, int domap)
{
  size_t idx = (size_t)blockIdx.x*256 + threadIdx.x;
  size_t tot = (size_t)N*K;
  if (idx >= tot) return;
  int n = idx / K, k = idx - (size_t)n*K;
  float vv = 0.f;
  if (src) vv = transp ? src[(size_t)k*sld + n] : src[(size_t)n*sld + k];
  int r = drow0 + (domap ? zmap(n) : n);
  dst[(size_t)r*dld + dcol0 + k] = f2bfs(vv);
}

__global__ void zero_k(float* p, int n){
  int i = blockIdx.x*256 + threadIdx.x;
  if (i < n) p[i] = 0.f;
}

__global__ void ln_inplace_k(short* kvp, const float* __restrict__ stats,
    const float* __restrict__ s, const float* __restrict__ bb)
{
  size_t i = (size_t)blockIdx.x*256 + threadIdx.x;
  int row = i >> 9, c = i & 511;
  float mu = stats[row*2] * (1.f/512.f);
  float var = stats[row*2 + 1] * (1.f/512.f) - mu*mu;
  float v = bfs2f(kvp[i]);
  kvp[i] = f2bfs((v - mu)*rsqrtf(var + 1e-5f)*s[c] + bb[c]);
}

__global__ void fill_k(short* Qbuf, short* Kbuf, float* vcur, short* oa_bf,
    float* st, const float* q0, const float* k0, const float* v0,
    const float* start, const float* strace)
{
  size_t i = (size_t)blockIdx.x*256 + threadIdx.x;
  const size_t R0 = 64u*1024u*32u;
  if (i < R0){
    int c = i & 31; int d = (i >> 5) & 1023;
    Qbuf[i] = (c < 25) ? f2bfs(q0[d]) : 0;
    Kbuf[i] = (c < 25) ? f2bfs(k0[d]) : 0;
    return;
  }
  i -= R0;
  if (i < 65536){
    int d = i & 1023; int b = i >> 10;
    vcur[i] = v0[d];
    oa_bf[(size_t)b*1536 + 512 + d] = f2bfs(start[d]);
    return;
  }
  i -= 65536;
  if (i < (size_t)25*65536){
    int p = (int)(i >> 16); int rem = (int)(i & 65535); int d = rem & 1023;
    st[i] = strace[d*25 + p];   // st transposed: [25][b*1024+d]
  }
}

__global__ __launch_bounds__(256) void cert_k(const float* __restrict__ preds, float* __restrict__ cert)
{
  int t = blockIdx.x, b = blockIdx.y, tid = threadIdx.x;
  __shared__ float red[256];
  float v[4]; float mx = -1e30f;
#pragma unroll
  for (int i = 0; i < 4; i++){
    int o = tid + i*256;
    v[i] = (o < 1000) ? preds[(size_t)b*50000 + (size_t)o*50 + t] : -1e30f;
    mx = fmaxf(mx, v[i]);
  }
  red[tid] = mx; __syncthreads();
  for (int s = 128; s; s >>= 1){ if (tid < s) red[tid] = fmaxf(red[tid], red[tid + s]); __syncthreads(); }
  float M = red[0]; __syncthreads();
  float z = 0.f, wsum = 0.f;
#pragma unroll
  for (int i = 0; i < 4; i++){
    int o = tid + i*256;
    if (o < 1000){ float p = v[i] - M; float e = __expf(p); z += e; wsum += e*p; }
  }
  red[tid] = z; __syncthreads();
  for (int s = 128; s; s >>= 1){ if (tid < s) red[tid] += red[tid + s]; __syncthreads(); }
  float Z = red[0]; __syncthreads();
  red[tid] = wsum; __syncthreads();
  for (int s = 128; s; s >>= 1){ if (tid < s) red[tid] += red[tid + s]; __syncthreads(); }
  float Wm = red[0];
  if (tid == 0){
    float ne = (__logf(Z) - Wm/Z) * 0.14476482730108392f; // 1/ln(1000)
    cert[b*100 + t] = ne;
    cert[b*100 + 50 + t] = 1.f - ne;
  }
}

__global__ void copy_sync_k(const float* __restrict__ S, float* __restrict__ out){
  int i = blockIdx.x*256 + threadIdx.x;
  out[i] = S[i];
}

// ============================== host ==============================
extern "C" void kernel_launch(void* const* d_in, const int* in_sizes, int n_in,
                              void* d_out, int out_size, void* d_ws, size_t ws_size,
                              hipStream_t stream)
{
  const float* x        = (const float*)d_in[0];
  const float* kv_w     = (const float*)d_in[1];
  const float* kv_b     = (const float*)d_in[2];
  const float* ln_kv_s  = (const float*)d_in[3];
  const float* ln_kv_b  = (const float*)d_in[4];
  const float* q_w      = (const float*)d_in[5];
  const float* q_b      = (const float*)d_in[6];
  const float* in_proj_w= (const float*)d_in[7];
  const float* in_proj_b= (const float*)d_in[8];
  const float* out_proj_w=(const float*)d_in[9];
  const float* out_proj_b=(const float*)d_in[10];
  const float* W_q      = (const float*)d_in[11];
  const float* W_k      = (const float*)d_in[12];
  const float* W_v      = (const float*)d_in[13];
  const float* syn_w    = (const float*)d_in[14];
  const float* syn_b    = (const float*)d_in[15];
  const float* syn_ln_s = (const float*)d_in[16];
  const float* syn_ln_b = (const float*)d_in[17];
  const float* nlm_w1   = (const float*)d_in[18];
  const float* nlm_b1   = (const float*)d_in[19];
  const float* nlm_w2   = (const float*)d_in[20];
  const float* nlm_b2   = (const float*)d_in[21];
  const float* start_act= (const float*)d_in[22];
  const float* strace   = (const float*)d_in[23];
  const float* out_w    = (const float*)d_in[24];
  const float* out_b    = (const float*)d_in[25];
  float* out = (float*)d_out;

  char* ws = (char*)d_ws;
  size_t off = 0;
  auto alloc = [&](size_t bytes)->char*{ char* p = ws + off; off = (off + bytes + 255) & ~(size_t)255; return p; };

  short* qw_B   = (short*)alloc((size_t)1024*512*2);
  short* opw_B  = (short*)alloc((size_t)512*512*2);
  short* Wfq    = (short*)alloc((size_t)512*1024*2);
  float* bfq    = (float*)alloc(512*4);
  short* Wz     = (short*)alloc((size_t)2048*1536*2);
  float* bz     = (float*)alloc(2048*4);
  short* Wqkv   = (short*)alloc((size_t)3072*1024*2);
  short* outwB  = (short*)alloc((size_t)1024*1024*2);
  short* kvw_B  = (short*)alloc((size_t)512*512*2);
  short* wkc_B  = (short*)alloc((size_t)512*512*2);
  short* wvc_B  = (short*)alloc((size_t)512*512*2);
  short* kvp    = (short*)alloc((size_t)12544*512*2);
  float* kvstats= (float*)alloc((size_t)25088*4);
  short* Kc     = (short*)alloc((size_t)12544*512*2);
  short* Vc     = (short*)alloc((size_t)12544*512*2);
  short* Qbuf   = (short*)alloc((size_t)64*1024*32*2);
  short* Kbuf   = (short*)alloc((size_t)64*1024*32*2);
  float* vcur   = (float*)alloc((size_t)65536*4);
  float* S      = (float*)alloc((size_t)65536*4);
  short* S_bf   = (short*)alloc((size_t)65536*2);
  short* SyncO  = (short*)alloc((size_t)64*50*1024*2);
  short* oa_bf  = (short*)alloc((size_t)64*1536*2);
  float* ubuf   = (float*)alloc((size_t)65536*4);
  float* stats  = (float*)alloc(128*4);
  float* st     = (float*)alloc((size_t)1638400*4);
  float* q0     = (float*)alloc(1024*4);
  float* k0     = (float*)alloc(1024*4);
  float* v0     = (float*)alloc(1024*4);
  unsigned* bar = (unsigned*)alloc(1024);
  (void)ws_size; (void)in_sizes; (void)n_in; (void)out_size;

  dim3 blk(256);

  // ---- prologue: weight prep ----
  zero_k<<<dim3(1), blk, 0, stream>>>((float*)bar, 256);
  castW_k<<<dim3((1024*512+255)/256), blk, 0, stream>>>(qw_B, 512, 0, 0, q_w, 1024, 1024, 512, 1, 0);
  castW_k<<<dim3((512*512+255)/256), blk, 0, stream>>>(opw_B, 512, 0, 0, out_proj_w, 512, 512, 512, 1, 0);
  castW_k<<<dim3((2048*1024+255)/256), blk, 0, stream>>>(Wz, 1536, 0, 512, syn_w + 512, 1536, 2048, 1024, 0, 1);
  castW_k<<<dim3((1024*1024+255)/256), blk, 0, stream>>>(Wqkv, 1024, 0, 0, W_q, 1024, 1024, 1024, 0, 0);
  castW_k<<<dim3((1024*1024+255)/256), blk, 0, stream>>>(Wqkv, 1024, 1024, 0, W_k, 1024, 1024, 1024, 0, 0);
  castW_k<<<dim3((1024*1024+255)/256), blk, 0, stream>>>(Wqkv, 1024, 2048, 0, W_v, 1024, 1024, 1024, 0, 0);
  castW_k<<<dim3((1000*1024+255)/256), blk, 0, stream>>>(outwB, 1024, 0, 0, out_w, 1024, 1000, 1024, 0, 0);
  castW_k<<<dim3((24*1024+255)/256), blk, 0, stream>>>(outwB, 1024, 1000, 0, nullptr, 0, 24, 1024, 0, 0);
  castW_k<<<dim3((512*512+255)/256), blk, 0, stream>>>(kvw_B, 512, 0, 0, kv_w, 512, 512, 512, 0, 0);
  castW_k<<<dim3((512*512+255)/256), blk, 0, stream>>>(wkc_B, 512, 0, 0, in_proj_w + 512*512, 512, 512, 512, 0, 0);
  castW_k<<<dim3((512*512+255)/256), blk, 0, stream>>>(wvc_B, 512, 0, 0, in_proj_w + 1024*512, 512, 512, 512, 0, 0);

  vecmat_k<<<dim3(256), blk, 0, stream>>>(W_q, 1024, start_act, nullptr, q0, 1024, 0);
  vecmat_k<<<dim3(256), blk, 0, stream>>>(W_k, 1024, start_act, nullptr, k0, 1024, 0);
  vecmat_k<<<dim3(256), blk, 0, stream>>>(W_v, 1024, start_act, nullptr, v0, 1024, 0);
  vecmat_k<<<dim3(128), blk, 0, stream>>>(in_proj_w, 512, q_b, in_proj_b, bfq, 512, 0);
  vecmat_k<<<dim3(512), blk, 0, stream>>>(syn_w, 1536, out_proj_b, syn_b, bz, 512, 1);

  gemm_tn<false, EpiBF16><<<dim3(8, 8), blk, 0, stream>>>(in_proj_w, 512, qw_B, 512, nullptr, 512, EpiBF16{Wfq, 1024, 0});
  gemm_tn<false, EpiBF16><<<dim3(4, 32), blk, 0, stream>>>(syn_w, 1536, opw_B, 512, nullptr, 512, EpiBF16{Wz, 1536, 1});

  zero_k<<<dim3(98), blk, 0, stream>>>(kvstats, 25088);
  gemm_tn<false, EpiKVpre><<<dim3(4, 196), blk, 0, stream>>>(x, 512, kvw_B, 512, kv_b, 512, EpiKVpre{kvp, kvstats});
  ln_inplace_k<<<dim3(25088), blk, 0, stream>>>(kvp, kvstats, ln_kv_s, ln_kv_b);
  gemm_tn<true, EpiBF16><<<dim3(4, 196), blk, 0, stream>>>(kvp, 512, wkc_B, 512, in_proj_b + 512, 512, EpiBF16{Kc, 512, 0});
  gemm_tn<true, EpiBF16><<<dim3(4, 196), blk, 0, stream>>>(kvp, 512, wvc_B, 512, in_proj_b + 1024, 512, EpiBF16{Vc, 512, 0});

  fill_k<<<dim3(14848), blk, 0, stream>>>(Qbuf, Kbuf, vcur, oa_bf, st, q0, k0, v0, start_act, strace);

  // ---- the whole 50-tick recurrence in ONE persistent kernel ----
  int nb = 256; // safe fallback (1 block/CU always resident)
  {
    int mb = 0;
    if (hipOccupancyMaxActiveBlocksPerMultiprocessor(&mb, reinterpret_cast<const void*>(tick_all_k), 256, 0) == hipSuccess && mb >= 1){
      int dev = 0; hipGetDevice(&dev);
      int ncu = 0;
      if (hipDeviceGetAttribute(&ncu, hipDeviceAttributeMultiprocessorCount, dev) != hipSuccess || ncu <= 0) ncu = 256;
      long cap = (long)mb * (long)ncu;
      nb = (int)(cap < 512 ? cap : 512);
    }
  }
  tick_all_k<<<dim3(nb), blk, 0, stream>>>(Wfq, bfq, Kc, Vc, Wz, bz, ubuf, stats,
      syn_ln_s, syn_ln_b, st, nlm_w1, nlm_b1, nlm_w2, nlm_b2, Wqkv,
      Qbuf, Kbuf, vcur, S, S_bf, SyncO, oa_bf, bar);

  // ---- epilogue: deferred output head ----
  gemm_tn<true, EpiPred><<<dim3(8, 50), blk, 0, stream>>>(SyncO, 1024, outwB, 1024, out_b, 1024, EpiPred{out});
  cert_k<<<dim3(50, 64), blk, 0, stream>>>(out, out + 3200000);
  copy_sync_k<<<dim3(256), blk, 0, stream>>>(S, out + 3206400);
}

// Round 4
// 7324.628 us; speedup vs baseline: 1.3179x; 1.3179x over previous
//
#include <hip/hip_runtime.h>
#include <hip/hip_bf16.h>

typedef __attribute__((ext_vector_type(8))) short short8v;
typedef __attribute__((ext_vector_type(4))) float f32x4;
typedef __attribute__((ext_vector_type(4))) float float4v;

#define DEV __device__ __forceinline__

DEV short f2bfs(float x){
  union { float f; unsigned u; } v; v.f = x;
  unsigned r = (v.u + 0x7FFFu + ((v.u >> 16) & 1u)) >> 16;
  return (short)(unsigned short)r;
}
DEV float bfs2f(short s){
  union { unsigned u; float f; } v; v.u = ((unsigned)(unsigned short)s) << 16;
  return v.f;
}
DEV float sigm(float x){ return 1.f / (1.f + __expf(-x)); }
// glu-pair interleave map: z-col j (0..2047) -> row n' so a-col and gate-col land
// 16 apart inside one wave's 32-col strip.
DEV int zmap(int j){ int g = (j >= 1024) ? 1 : 0; int i = j - (g << 10); return (i & 15) + ((i >> 4) << 5) + (g << 4); }

// Coherent (agent-scope, L2-bypassing) loads for cross-XCD intermediates whose
// addresses are reused across ticks (stale-clean-L2-copy hazard).
DEV int aldi(const void* p){ return __hip_atomic_load((const int*)p, __ATOMIC_RELAXED, __HIP_MEMORY_SCOPE_AGENT); }
DEV float aldf(const void* p){ return __hip_atomic_load((const float*)p, __ATOMIC_RELAXED, __HIP_MEMORY_SCOPE_AGENT); }
DEV long long aldll(const void* p){ return __hip_atomic_load((const long long*)p, __ATOMIC_RELAXED, __HIP_MEMORY_SCOPE_AGENT); }

// ================= device-scope grid barrier =================
// Release (writeback-L2) on arrival; NO agent-acquire (no L2 invalidate!) —
// weights/Kc/Vc stay L2-resident for all 50 ticks. Readers of mutable shared
// state use scoped atomic loads; ring-buffered intermediates get fresh
// addresses each tick (first-touch reads are always clean).
DEV void gbar(unsigned* bar, int nb){
  __syncthreads();
  if (threadIdx.x == 0){
    __builtin_amdgcn_fence(__ATOMIC_RELEASE, "agent");   // waitcnt + buffer_wbl2 (no inv)
    unsigned* gen = bar + 128;
    unsigned g = __hip_atomic_load(gen, __ATOMIC_RELAXED, __HIP_MEMORY_SCOPE_AGENT);
    int lane = blockIdx.x & 7;
    __hip_atomic_fetch_add(bar + lane*16, 1u, __ATOMIC_RELAXED, __HIP_MEMORY_SCOPE_AGENT);
    if (blockIdx.x == 0){
      unsigned sum;
      do {
        sum = 0;
#pragma unroll
        for (int i = 0; i < 8; i++) sum += __hip_atomic_load(bar + i*16, __ATOMIC_RELAXED, __HIP_MEMORY_SCOPE_AGENT);
      } while (sum < (unsigned)nb);
#pragma unroll
      for (int i = 0; i < 8; i++) __hip_atomic_store(bar + i*16, 0u, __ATOMIC_RELAXED, __HIP_MEMORY_SCOPE_AGENT);
      __hip_atomic_store(gen, g + 1u, __ATOMIC_RELEASE, __HIP_MEMORY_SCOPE_AGENT);
    } else {
      while (__hip_atomic_load(gen, __ATOMIC_RELAXED, __HIP_MEMORY_SCOPE_AGENT) == g)
        __builtin_amdgcn_s_sleep(1);
    }
  }
  __syncthreads();
}

// ================= persistent-kernel tick phases =================

// Phase 1: fused Qh projection + cross-attention. unit u -> (h = u&7, b = u>>3)
// S_bf read via agent loads (reused address); Wfq/Kc/Vc plain (L2-resident).
DEV void phase_qhcross(int u, const short* __restrict__ Wfq, const float* __restrict__ bfq,
    const short* __restrict__ Kc, const short* __restrict__ Vc, const short* __restrict__ S_bf,
    short* __restrict__ oaC, float* __restrict__ stats, float* smf, int tid, int zero_stats)
{
  float* Srow = smf;          // 1024
  float* qs   = smf + 1024;   // 64
  float* wsm  = smf + 1088;   // 256
  float* red  = smf + 1344;   // 256
  int h = u & 7, b = u >> 3;
  __syncthreads();
  const int* spi = (const int*)(S_bf + b*1024);
#pragma unroll
  for (int r = 0; r < 2; r++){
    int idx = tid + r*256;
    int pv = aldi(spi + idx);
    Srow[idx*2]     = bfs2f((short)(pv & 0xffff));
    Srow[idx*2 + 1] = bfs2f((short)(((unsigned)pv) >> 16));
  }
  if (zero_stats && tid < 128) stats[tid] = 0.f;
  __syncthreads();
  {
    int d = tid & 63, c = tid >> 6;
    const short* wp = Wfq + (size_t)(h*64 + d)*1024 + c*256;
    const float* srp = Srow + c*256;
    float acc = 0.f;
#pragma unroll 4
    for (int i = 0; i < 256; i += 8){
      short8v wv = *(const short8v*)(wp + i);
#pragma unroll
      for (int j = 0; j < 8; j++) acc += bfs2f(wv[j]) * srp[i + j];
    }
    red[tid] = acc;
  }
  __syncthreads();
  if (tid < 64) qs[tid] = bfq[h*64 + tid] + red[tid] + red[tid+64] + red[tid+128] + red[tid+192];
  __syncthreads();
  // cross-attention
  float sv = -1e30f;
  if (tid < 196){
    const short* kp = Kc + ((size_t)(b*196 + tid)*512 + h*64);
    float acc = 0.f;
#pragma unroll
    for (int j = 0; j < 64; j += 8){
      short8v kv8 = *(const short8v*)(kp + j);
#pragma unroll
      for (int u8 = 0; u8 < 8; u8++) acc += bfs2f(kv8[u8]) * qs[j + u8];
    }
    sv = acc * 0.125f;
  }
  red[tid] = sv; __syncthreads();
  for (int s = 128; s > 0; s >>= 1){ if (tid < s) red[tid] = fmaxf(red[tid], red[tid+s]); __syncthreads(); }
  float M = red[0]; __syncthreads();
  float e = (tid < 196) ? __expf(sv - M) : 0.f;
  wsm[tid] = e; red[tid] = e; __syncthreads();
  for (int s = 128; s > 0; s >>= 1){ if (tid < s) red[tid] += red[tid+s]; __syncthreads(); }
  float Z = red[0]; __syncthreads();
  int dd = tid & 63, cc = tid >> 6;
  float acc = 0.f;
  for (int s = cc; s < 196; s += 4) acc += wsm[s] * bfs2f(Vc[(size_t)(b*196 + s)*512 + h*64 + dd]);
  red[tid] = acc; __syncthreads();
  if (tid < 64){
    float o = (red[tid] + red[tid+64] + red[tid+128] + red[tid+192]) / Z;
    oaC[(size_t)b*1536 + h*64 + tid] = f2bfs(o);
  }
  __syncthreads();
}

// Phase 2: GLU GEMM, 64 units (32-col strips of N=2048), 4-wave K-split over K=1536.
// A (oaC) is fresh-per-tick ring -> plain 16B loads (first-touch coherent).
DEV void phase_glu(int u, const short* __restrict__ Wz, const float* __restrict__ bz,
    const short* __restrict__ oaC, float* __restrict__ ubuf, float* __restrict__ stats,
    float* smf, int tid)
{
  float* part   = smf;        // 4*64*32 = 8192
  float* statsl = smf + 8192; // 128
  int n0 = u * 32;
  __syncthreads();
  if (tid < 128) statsl[tid] = 0.f;
  int w = tid >> 6, l15 = tid & 15, l4 = (tid >> 4) & 3;
  f32x4 acc[4][2];
#pragma unroll
  for (int mi = 0; mi < 4; mi++)
#pragma unroll
    for (int ni = 0; ni < 2; ni++) acc[mi][ni] = (f32x4){0.f,0.f,0.f,0.f};
#pragma unroll 2
  for (int it = 0; it < 12; it++){
    int ks = w*384 + it*32 + l4*8;
    short8v a4[4], bb[2];
#pragma unroll
    for (int mi = 0; mi < 4; mi++)
      a4[mi] = *(const short8v*)(oaC + (size_t)(mi*16 + l15)*1536 + ks);
#pragma unroll
    for (int ni = 0; ni < 2; ni++)
      bb[ni] = *(const short8v*)(Wz + (size_t)(n0 + ni*16 + l15)*1536 + ks);
#pragma unroll
    for (int mi = 0; mi < 4; mi++)
#pragma unroll
      for (int ni = 0; ni < 2; ni++)
        acc[mi][ni] = __builtin_amdgcn_mfma_f32_16x16x32_bf16(a4[mi], bb[ni], acc[mi][ni], 0, 0, 0);
  }
#pragma unroll
  for (int mi = 0; mi < 4; mi++)
#pragma unroll
    for (int ni = 0; ni < 2; ni++)
#pragma unroll
      for (int r = 0; r < 4; r++)
        part[w*2048 + (mi*16 + l4*4 + r)*32 + ni*16 + l15] = acc[mi][ni][r];
  __syncthreads();
  int m = tid >> 2;
  float s1 = 0.f, s2 = 0.f;
#pragma unroll
  for (int e = 0; e < 4; e++){
    int j = ((tid & 3) << 2) + e;
    float a = part[m*32 + j] + part[2048 + m*32 + j] + part[4096 + m*32 + j] + part[6144 + m*32 + j] + bz[n0 + j];
    float g = part[m*32 + 16 + j] + part[2048 + m*32 + 16 + j] + part[4096 + m*32 + 16 + j] + part[6144 + m*32 + 16 + j] + bz[n0 + 16 + j];
    float uv = a * sigm(g);
    ubuf[(size_t)m*1024 + (n0 >> 1) + j] = uv;
    s1 += uv; s2 += uv*uv;
  }
  atomicAdd(&statsl[m], s1); atomicAdd(&statsl[64 + m], s2);
  __syncthreads();
  if (tid < 64){ atomicAdd(&stats[tid], statsl[tid]); atomicAdd(&stats[64 + tid], statsl[64 + tid]); }
  __syncthreads();
}

// Phase 3: LN + trace append + per-neuron NLM. 512 units (stable block->u map ->
// st is same-block-private across ticks, plain loads stay L2-hot).
DEV void phase_nlm(int u, const float* __restrict__ ubuf, const float* __restrict__ stats,
    const float* __restrict__ g_s, const float* __restrict__ g_b, float* __restrict__ st,
    const float* __restrict__ w1, const float* __restrict__ b1,
    const float* __restrict__ w2, const float* __restrict__ b2,
    short* __restrict__ oaN, int t, float* smf, int tid)
{
  float* pl = smf; // [2][8][16][16] = 4096
  int x = u & 63, y = u >> 6;
  int d_i = tid & 15, b_i = (tid >> 4) & 7, half = tid >> 7;
  int d = x*16 + d_i, b = y*8 + b_i;
  float mu = aldf(stats + b) * (1.f/1024.f);
  float var = aldf(stats + 64 + b) * (1.f/1024.f) - mu*mu;
  float rs = rsqrtf(var + 1e-5f);
  float uv = aldf(ubuf + b*1024 + d);
  float state = (uv - mu)*rs*g_s[d] + g_b[d];
  int slot = t % 25;
  if (half == 0) st[(size_t)slot*65536 + b*1024 + d] = state;
  float pre[16];
#pragma unroll
  for (int hh = 0; hh < 16; hh++) pre[hh] = b1[d*32 + half*16 + hh];
  int p0 = (t + 1) % 25;
#pragma unroll 5
  for (int m = 0; m < 25; m++){
    int p = p0 + m; if (p >= 25) p -= 25;
    float sm = (p == slot) ? state : st[(size_t)p*65536 + b*1024 + d];
#pragma unroll
    for (int hh = 0; hh < 16; hh++) pre[hh] += sm * w1[(size_t)(m*32 + half*16 + hh)*1024 + d];
  }
  __syncthreads();
#pragma unroll
  for (int hh = 0; hh < 16; hh++) pl[((half*8 + b_i)*16 + hh)*16 + d_i] = pre[hh];
  __syncthreads();
  if (half == 0){
    float p2a = b2[d*2 + 0], p2g = b2[d*2 + 1];
#pragma unroll
    for (int i = 0; i < 16; i++){
      float hv = pl[((b_i)*16 + i)*16 + d_i] * sigm(pl[((8 + b_i)*16 + i)*16 + d_i]);
      p2a += hv * w2[(size_t)(i*2 + 0)*1024 + d];
      p2g += hv * w2[(size_t)(i*2 + 1)*1024 + d];
    }
    float act = p2a * sigm(p2g);
    oaN[(size_t)b*1536 + 512 + d] = f2bfs(act);
  }
  __syncthreads();
}

// Phase 4: QKV GEMM, 96 units. A = act part of oaN (fresh ring, plain loads).
DEV void phase_qkv(int u, const short* __restrict__ Wqkv, const short* __restrict__ act_bf,
    short* __restrict__ Qb, short* __restrict__ Kb, float* __restrict__ vc, int slot,
    float* smf, int tid)
{
  float* part = smf; // 8192
  int n0 = u * 32;
  __syncthreads();
  int w = tid >> 6, l15 = tid & 15, l4 = (tid >> 4) & 3;
  f32x4 acc[4][2];
#pragma unroll
  for (int mi = 0; mi < 4; mi++)
#pragma unroll
    for (int ni = 0; ni < 2; ni++) acc[mi][ni] = (f32x4){0.f,0.f,0.f,0.f};
#pragma unroll 2
  for (int it = 0; it < 8; it++){
    int ks = w*256 + it*32 + l4*8;
    short8v a4[4], bb[2];
#pragma unroll
    for (int mi = 0; mi < 4; mi++)
      a4[mi] = *(const short8v*)(act_bf + (size_t)(mi*16 + l15)*1536 + ks);
#pragma unroll
    for (int ni = 0; ni < 2; ni++)
      bb[ni] = *(const short8v*)(Wqkv + (size_t)(n0 + ni*16 + l15)*1024 + ks);
#pragma unroll
    for (int mi = 0; mi < 4; mi++)
#pragma unroll
      for (int ni = 0; ni < 2; ni++)
        acc[mi][ni] = __builtin_amdgcn_mfma_f32_16x16x32_bf16(a4[mi], bb[ni], acc[mi][ni], 0, 0, 0);
  }
#pragma unroll
  for (int mi = 0; mi < 4; mi++)
#pragma unroll
    for (int ni = 0; ni < 2; ni++)
#pragma unroll
      for (int r = 0; r < 4; r++)
        part[w*2048 + (mi*16 + l4*4 + r)*32 + ni*16 + l15] = acc[mi][ni][r];
  __syncthreads();
  int m = tid >> 2;
#pragma unroll
  for (int e = 0; e < 8; e++){
    int nl = ((tid & 3) << 3) + e;
    float v = part[m*32 + nl] + part[2048 + m*32 + nl] + part[4096 + m*32 + nl] + part[6144 + m*32 + nl];
    int n = n0 + nl;
    if (n < 1024)      Qb[((size_t)m*1024 + n)*32 + slot] = f2bfs(v);
    else if (n < 2048) Kb[((size_t)m*1024 + (n-1024))*32 + slot] = f2bfs(v);
    else               vc[(size_t)m*1024 + (n-2048)] = v;
  }
  __syncthreads();
}

// Phase 5: neuron-sync attention. Qbuf/Kbuf/vcur have reused addresses -> coherent loads (8B).
DEV void phase_sync(int u, int t, const short* __restrict__ Qbuf, const short* __restrict__ Kbuf,
    const float* __restrict__ vcur, float* __restrict__ S, short* __restrict__ S_bf,
    short* __restrict__ SyncO, float* smf, int tid)
{
  short8v* qlds = (short8v*)smf;
  short8v* klds = ((short8v*)smf) + 512;
  long long* ql = (long long*)qlds; long long* kl = (long long*)klds;
  int h = u & 7, b = u >> 3;
  __syncthreads();
  const short* qg = Qbuf + ((size_t)b*1024 + h*128)*32;
  const short* kg = Kbuf + ((size_t)b*1024 + h*128)*32;
#pragma unroll
  for (int it = 0; it < 2; it++){
    int ch = tid + 256*it;
    int d = ch >> 2, c = ch & 3;
    int cs = c ^ ((d >> 1) & 3);
    const long long* qp = (const long long*)qg + d*8 + c*2;
    const long long* kp = (const long long*)kg + d*8 + c*2;
#pragma unroll
    for (int j = 0; j < 2; j++){
      ql[(d*4 + cs)*2 + j] = aldll(qp + j);
      kl[(d*4 + cs)*2 + j] = aldll(kp + j);
    }
  }
  __syncthreads();
  int w = tid >> 6, l15 = tid & 15, l4 = (tid >> 4) & 3;
  short8v af[2], bfr[8];
#pragma unroll
  for (int mi2 = 0; mi2 < 2; mi2++){
    int d = (2*w + mi2)*16 + l15;
    af[mi2] = qlds[d*4 + (l4 ^ ((d >> 1) & 3))];
  }
#pragma unroll
  for (int ni = 0; ni < 8; ni++){
    int e = ni*16 + l15;
    bfr[ni] = klds[e*4 + (l4 ^ ((e >> 1) & 3))];
  }
  f32x4 acc[2][8];
#pragma unroll
  for (int mi2 = 0; mi2 < 2; mi2++)
#pragma unroll
    for (int ni = 0; ni < 8; ni++)
      acc[mi2][ni] = (f32x4){0.f,0.f,0.f,0.f};
#pragma unroll
  for (int mi2 = 0; mi2 < 2; mi2++)
#pragma unroll
    for (int ni = 0; ni < 8; ni++)
      acc[mi2][ni] = __builtin_amdgcn_mfma_f32_16x16x32_bf16(af[mi2], bfr[ni], acc[mi2][ni], 0, 0, 0);
  float Vv[8];
#pragma unroll
  for (int ni = 0; ni < 8; ni++) Vv[ni] = aldf(vcur + b*1024 + h*128 + ni*16 + l15);
  const float scale = 0.08838834764831845f; // 1/sqrt(128)
#pragma unroll
  for (int mi2 = 0; mi2 < 2; mi2++)
#pragma unroll
    for (int r = 0; r < 4; r++){
      float sv[8]; float mx = -1e30f;
#pragma unroll
      for (int ni = 0; ni < 8; ni++){ sv[ni] = acc[mi2][ni][r]*scale; mx = fmaxf(mx, sv[ni]); }
#pragma unroll
      for (int off = 1; off < 16; off <<= 1) mx = fmaxf(mx, __shfl_xor(mx, off));
      float den = 0.f, num = 0.f;
#pragma unroll
      for (int ni = 0; ni < 8; ni++){ float p = __expf(sv[ni] - mx); den += p; num += p*Vv[ni]; }
#pragma unroll
      for (int off = 1; off < 16; off <<= 1){ den += __shfl_xor(den, off); num += __shfl_xor(num, off); }
      if (l15 == 0){
        int d = (2*w + mi2)*16 + l4*4 + r;
        float att = num / den;
        int oi = b*1024 + d*8 + h;
        S[oi] = att;
        S_bf[oi] = f2bfs(att);
        if (t >= 0) SyncO[((size_t)b*50 + t)*1024 + d*8 + h] = f2bfs(att);
      }
    }
  __syncthreads();
}

// ================= the persistent 50-tick kernel =================
__global__ __launch_bounds__(256, 2) void tick_all_k(
    const short* __restrict__ Wfq, const float* __restrict__ bfq,
    const short* __restrict__ Kc, const short* __restrict__ Vc,
    const short* __restrict__ Wz, const float* __restrict__ bz,
    float* __restrict__ ubuf, float* __restrict__ stats,
    const float* __restrict__ g_s, const float* __restrict__ g_b,
    float* __restrict__ st,
    const float* __restrict__ w1, const float* __restrict__ b1,
    const float* __restrict__ w2, const float* __restrict__ b2,
    const short* __restrict__ Wqkv,
    short* __restrict__ Qbuf, short* __restrict__ Kbuf, float* __restrict__ vcur,
    float* __restrict__ S, short* __restrict__ S_bf, short* __restrict__ SyncO,
    short* __restrict__ oaR, unsigned* bar)
{
  __shared__ float smf[8320]; // 33.3 KB: max overlay (phase2/4 partials)
  const int tid = threadIdx.x;
  const int bid = blockIdx.x;
  const int nb  = gridDim.x;

  // initial synchronisation (t = -1): S_bf <- sync_attn(hist0, act0)
  for (int u = bid; u < 512; u += nb) phase_sync(u, -1, Qbuf, Kbuf, vcur, S, S_bf, SyncO, smf, tid);
  gbar(bar, nb);

#pragma unroll 1
  for (int t = 0; t < 50; t++){
    short* oaC = oaR + (size_t)t * 98304;        // [cross_t | act_{t-1}]
    short* oaN = oaR + (size_t)(t + 1) * 98304;  // act_t written here
    for (int u = bid; u < 512; u += nb)
      phase_qhcross(u, Wfq, bfq, Kc, Vc, S_bf, oaC, stats, smf, tid, u == 0);
    gbar(bar, nb);
    for (int u = bid; u < 64; u += nb)
      phase_glu(u, Wz, bz, oaC, ubuf, stats, smf, tid);
    gbar(bar, nb);
    for (int u = bid; u < 512; u += nb)
      phase_nlm(u, ubuf, stats, g_s, g_b, st, w1, b1, w2, b2, oaN, t, smf, tid);
    gbar(bar, nb);
    for (int u = bid; u < 96; u += nb)
      phase_qkv(u, Wqkv, oaN + 512, Qbuf, Kbuf, vcur, t % 25, smf, tid);
    gbar(bar, nb);
    for (int u = bid; u < 512; u += nb)
      phase_sync(u, t, Qbuf, Kbuf, vcur, S, S_bf, SyncO, smf, tid);
    gbar(bar, nb);
  }
}

// ================= prologue / epilogue kernels (unchanged math) =================
struct EpiBF16 {
  short* C; int ldc; int domap;
  DEV void op(const f32x4 (&acc)[4][2], int m0, int n0, int l15, int l4, const float* bias) const {
#pragma unroll
    for (int mi = 0; mi < 4; mi++)
#pragma unroll
      for (int ni = 0; ni < 2; ni++){
        int n = n0 + ni*16 + l15;
        float bb = bias ? bias[n] : 0.f;
#pragma unroll
        for (int r = 0; r < 4; r++){
          int m = m0 + mi*16 + l4*4 + r;
          int mr = domap ? zmap(m) : m;
          C[(size_t)mr*ldc + n] = f2bfs(acc[mi][ni][r] + bb);
        }
      }
  }
};

struct EpiPred { // m = b*50+t ; out[b][n][t]
  float* outp;
  DEV void op(const f32x4 (&acc)[4][2], int m0, int n0, int l15, int l4, const float* bias) const {
#pragma unroll
    for (int mi = 0; mi < 4; mi++)
#pragma unroll
      for (int ni = 0; ni < 2; ni++){
        int n = n0 + ni*16 + l15;
        if (n >= 1000) continue;
        float bb = bias[n];
#pragma unroll
        for (int r = 0; r < 4; r++){
          int m = m0 + mi*16 + l4*4 + r;
          int b = m / 50, tt = m - b*50;
          outp[(size_t)b*50000 + (size_t)n*50 + tt] = acc[mi][ni][r] + bb;
        }
      }
  }
};

struct EpiKVpre { // bf16 store + per-row LN stats
  short* C; float* stats;
  DEV void op(const f32x4 (&acc)[4][2], int m0, int n0, int l15, int l4, const float* bias) const {
    float b0 = bias[n0 + l15], b1 = bias[n0 + 16 + l15];
#pragma unroll
    for (int mi = 0; mi < 4; mi++)
#pragma unroll
      for (int r = 0; r < 4; r++){
        int m = m0 + mi*16 + l4*4 + r;
        float v0 = acc[mi][0][r] + b0;
        float v1 = acc[mi][1][r] + b1;
        C[(size_t)m*512 + n0 + l15]      = f2bfs(v0);
        C[(size_t)m*512 + n0 + 16 + l15] = f2bfs(v1);
        float s = v0 + v1, s2 = v0*v0 + v1*v1;
#pragma unroll
        for (int off = 1; off < 16; off <<= 1){ s += __shfl_xor(s, off); s2 += __shfl_xor(s2, off); }
        if (l15 == 0){ atomicAdd(&stats[m*2], s); atomicAdd(&stats[m*2 + 1], s2); }
      }
  }
};

template<bool ABF16, typename EPI>
__global__ __launch_bounds__(256) void gemm_tn(const void* __restrict__ Aptr, int lda,
    const short* __restrict__ Bw, int ldb, const float* __restrict__ bias,
    int K, EPI epi)
{
  int tid = threadIdx.x;
  const int w = tid >> 6, l15 = tid & 15, l4 = (tid >> 4) & 3;
  const int m0 = blockIdx.y * 64;
  const int n0 = blockIdx.x * 128 + w * 32;
  f32x4 acc[4][2];
#pragma unroll
  for (int mi = 0; mi < 4; mi++)
#pragma unroll
    for (int ni = 0; ni < 2; ni++)
      acc[mi][ni] = (f32x4){0.f, 0.f, 0.f, 0.f};
#pragma unroll 4
  for (int kk = 0; kk < K; kk += 32){
    const int ks = kk + l4*8;
    short8v a[4], bfr[2];
#pragma unroll
    for (int mi = 0; mi < 4; mi++){
      const size_t row = (size_t)(m0 + mi*16 + l15);
      if (ABF16){
        a[mi] = *(const short8v*)((const short*)Aptr + row*lda + ks);
      } else {
        const float* ap = (const float*)Aptr + row*lda + ks;
        float4v f0 = *(const float4v*)ap;
        float4v f1 = *(const float4v*)(ap + 4);
        short8v tt;
        tt[0]=f2bfs(f0[0]); tt[1]=f2bfs(f0[1]); tt[2]=f2bfs(f0[2]); tt[3]=f2bfs(f0[3]);
        tt[4]=f2bfs(f1[0]); tt[5]=f2bfs(f1[1]); tt[6]=f2bfs(f1[2]); tt[7]=f2bfs(f1[3]);
        a[mi] = tt;
      }
    }
#pragma unroll
    for (int ni = 0; ni < 2; ni++)
      bfr[ni] = *(const short8v*)(Bw + (size_t)(n0 + ni*16 + l15)*ldb + ks);
#pragma unroll
    for (int mi = 0; mi < 4; mi++)
#pragma unroll
      for (int ni = 0; ni < 2; ni++)
        acc[mi][ni] = __builtin_amdgcn_mfma_f32_16x16x32_bf16(a[mi], bfr[ni], acc[mi][ni], 0, 0, 0);
  }
  epi.op(acc, m0, n0, l15, l4, bias);
}

__global__ __launch_bounds__(256) void vecmat_k(const float* __restrict__ W, int ldw,
    const float* __restrict__ v, const float* __restrict__ add, float* __restrict__ out, int K, int domap)
{
  int w = threadIdx.x >> 6, l = threadIdx.x & 63;
  int n = blockIdx.x*4 + w;
  float s = 0.f;
  for (int k = l; k < K; k += 64) s += W[(size_t)n*ldw + k]*v[k];
#pragma unroll
  for (int off = 32; off; off >>= 1) s += __shfl_xor(s, off);
  if (l == 0){ float o = s + (add ? add[n] : 0.f); out[domap ? zmap(n) : n] = o; }
}

__global__ void castW_k(short* dst, int dld, int drow0, int dcol0,
    const float* src, int sld, int N, int K, int transp, int domap)
{
  size_t idx = (size_t)blockIdx.x*256 + threadIdx.x;
  size_t tot = (size_t)N*K;
  if (idx >= tot) return;
  int n = idx / K, k = idx - (size_t)n*K;
  float vv = 0.f;
  if (src) vv = transp ? src[(size_t)k*sld + n] : src[(size_t)n*sld + k];
  int r = drow0 + (domap ? zmap(n) : n);
  dst[(size_t)r*dld + dcol0 + k] = f2bfs(vv);
}

__global__ void zero_k(float* p, int n){
  int i = blockIdx.x*256 + threadIdx.x;
  if (i < n) p[i] = 0.f;
}

__global__ void ln_inplace_k(short* kvp, const float* __restrict__ stats,
    const float* __restrict__ s, const float* __restrict__ bb)
{
  size_t i = (size_t)blockIdx.x*256 + threadIdx.x;
  int row = i >> 9, c = i & 511;
  float mu = stats[row*2] * (1.f/512.f);
  float var = stats[row*2 + 1] * (1.f/512.f) - mu*mu;
  float v = bfs2f(kvp[i]);
  kvp[i] = f2bfs((v - mu)*rsqrtf(var + 1e-5f)*s[c] + bb[c]);
}

__global__ void fill_k(short* Qbuf, short* Kbuf, float* vcur, short* oaR,
    float* st, const float* q0, const float* k0, const float* v0,
    const float* start, const float* strace)
{
  size_t i = (size_t)blockIdx.x*256 + threadIdx.x;
  const size_t R0 = 64u*1024u*32u;
  if (i < R0){
    int c = i & 31; int d = (i >> 5) & 1023;
    Qbuf[i] = (c < 25) ? f2bfs(q0[d]) : 0;
    Kbuf[i] = (c < 25) ? f2bfs(k0[d]) : 0;
    return;
  }
  i -= R0;
  if (i < 65536){
    int d = i & 1023; int b = i >> 10;
    vcur[i] = v0[d];
    oaR[(size_t)b*1536 + 512 + d] = f2bfs(start[d]);
    return;
  }
  i -= 65536;
  if (i < (size_t)25*65536){
    int p = (int)(i >> 16); int rem = (int)(i & 65535); int d = rem & 1023;
    st[i] = strace[d*25 + p];   // st transposed: [25][b*1024+d]
  }
}

__global__ __launch_bounds__(256) void cert_k(const float* __restrict__ preds, float* __restrict__ cert)
{
  int t = blockIdx.x, b = blockIdx.y, tid = threadIdx.x;
  __shared__ float red[256];
  float v[4]; float mx = -1e30f;
#pragma unroll
  for (int i = 0; i < 4; i++){
    int o = tid + i*256;
    v[i] = (o < 1000) ? preds[(size_t)b*50000 + (size_t)o*50 + t] : -1e30f;
    mx = fmaxf(mx, v[i]);
  }
  red[tid] = mx; __syncthreads();
  for (int s = 128; s; s >>= 1){ if (tid < s) red[tid] = fmaxf(red[tid], red[tid + s]); __syncthreads(); }
  float M = red[0]; __syncthreads();
  float z = 0.f, wsum = 0.f;
#pragma unroll
  for (int i = 0; i < 4; i++){
    int o = tid + i*256;
    if (o < 1000){ float p = v[i] - M; float e = __expf(p); z += e; wsum += e*p; }
  }
  red[tid] = z; __syncthreads();
  for (int s = 128; s; s >>= 1){ if (tid < s) red[tid] += red[tid + s]; __syncthreads(); }
  float Z = red[0]; __syncthreads();
  red[tid] = wsum; __syncthreads();
  for (int s = 128; s; s >>= 1){ if (tid < s) red[tid] += red[tid + s]; __syncthreads(); }
  float Wm = red[0];
  if (tid == 0){
    float ne = (__logf(Z) - Wm/Z) * 0.14476482730108392f; // 1/ln(1000)
    cert[b*100 + t] = ne;
    cert[b*100 + 50 + t] = 1.f - ne;
  }
}

__global__ void copy_sync_k(const float* __restrict__ S, float* __restrict__ out){
  int i = blockIdx.x*256 + threadIdx.x;
  out[i] = S[i];
}

// ============================== host ==============================
extern "C" void kernel_launch(void* const* d_in, const int* in_sizes, int n_in,
                              void* d_out, int out_size, void* d_ws, size_t ws_size,
                              hipStream_t stream)
{
  const float* x        = (const float*)d_in[0];
  const float* kv_w     = (const float*)d_in[1];
  const float* kv_b     = (const float*)d_in[2];
  const float* ln_kv_s  = (const float*)d_in[3];
  const float* ln_kv_b  = (const float*)d_in[4];
  const float* q_w      = (const float*)d_in[5];
  const float* q_b      = (const float*)d_in[6];
  const float* in_proj_w= (const float*)d_in[7];
  const float* in_proj_b= (const float*)d_in[8];
  const float* out_proj_w=(const float*)d_in[9];
  const float* out_proj_b=(const float*)d_in[10];
  const float* W_q      = (const float*)d_in[11];
  const float* W_k      = (const float*)d_in[12];
  const float* W_v      = (const float*)d_in[13];
  const float* syn_w    = (const float*)d_in[14];
  const float* syn_b    = (const float*)d_in[15];
  const float* syn_ln_s = (const float*)d_in[16];
  const float* syn_ln_b = (const float*)d_in[17];
  const float* nlm_w1   = (const float*)d_in[18];
  const float* nlm_b1   = (const float*)d_in[19];
  const float* nlm_w2   = (const float*)d_in[20];
  const float* nlm_b2   = (const float*)d_in[21];
  const float* start_act= (const float*)d_in[22];
  const float* strace   = (const float*)d_in[23];
  const float* out_w    = (const float*)d_in[24];
  const float* out_b    = (const float*)d_in[25];
  float* out = (float*)d_out;

  char* ws = (char*)d_ws;
  size_t off = 0;
  auto alloc = [&](size_t bytes)->char*{ char* p = ws + off; off = (off + bytes + 255) & ~(size_t)255; return p; };

  short* qw_B   = (short*)alloc((size_t)1024*512*2);
  short* opw_B  = (short*)alloc((size_t)512*512*2);
  short* Wfq    = (short*)alloc((size_t)512*1024*2);
  float* bfq    = (float*)alloc(512*4);
  short* Wz     = (short*)alloc((size_t)2048*1536*2);
  float* bz     = (float*)alloc(2048*4);
  short* Wqkv   = (short*)alloc((size_t)3072*1024*2);
  short* outwB  = (short*)alloc((size_t)1024*1024*2);
  short* kvw_B  = (short*)alloc((size_t)512*512*2);
  short* wkc_B  = (short*)alloc((size_t)512*512*2);
  short* wvc_B  = (short*)alloc((size_t)512*512*2);
  short* kvp    = (short*)alloc((size_t)12544*512*2);   // aliased as oa ring in tick_all
  float* kvstats= (float*)alloc((size_t)25088*4);
  short* Kc     = (short*)alloc((size_t)12544*512*2);
  short* Vc     = (short*)alloc((size_t)12544*512*2);
  short* Qbuf   = (short*)alloc((size_t)64*1024*32*2);
  short* Kbuf   = (short*)alloc((size_t)64*1024*32*2);
  float* vcur   = (float*)alloc((size_t)65536*4);
  float* S      = (float*)alloc((size_t)65536*4);
  short* S_bf   = (short*)alloc((size_t)65536*2);
  short* SyncO  = (short*)alloc((size_t)64*50*1024*2);
  float* ubuf   = (float*)alloc((size_t)65536*4);
  float* stats  = (float*)alloc(128*4);
  float* st     = (float*)alloc((size_t)1638400*4);
  float* q0     = (float*)alloc(1024*4);
  float* k0     = (float*)alloc(1024*4);
  float* v0     = (float*)alloc(1024*4);
  unsigned* bar = (unsigned*)alloc(1024);
  short* oaR    = kvp; // 51 * 98304 shorts = 10.0 MB <= kvp's 12.8 MB; kvp dead after prologue
  (void)ws_size; (void)in_sizes; (void)n_in; (void)out_size;

  dim3 blk(256);

  // ---- prologue: weight prep ----
  zero_k<<<dim3(1), blk, 0, stream>>>((float*)bar, 256);
  castW_k<<<dim3((1024*512+255)/256), blk, 0, stream>>>(qw_B, 512, 0, 0, q_w, 1024, 1024, 512, 1, 0);
  castW_k<<<dim3((512*512+255)/256), blk, 0, stream>>>(opw_B, 512, 0, 0, out_proj_w, 512, 512, 512, 1, 0);
  castW_k<<<dim3((2048*1024+255)/256), blk, 0, stream>>>(Wz, 1536, 0, 512, syn_w + 512, 1536, 2048, 1024, 0, 1);
  castW_k<<<dim3((1024*1024+255)/256), blk, 0, stream>>>(Wqkv, 1024, 0, 0, W_q, 1024, 1024, 1024, 0, 0);
  castW_k<<<dim3((1024*1024+255)/256), blk, 0, stream>>>(Wqkv, 1024, 1024, 0, W_k, 1024, 1024, 1024, 0, 0);
  castW_k<<<dim3((1024*1024+255)/256), blk, 0, stream>>>(Wqkv, 1024, 2048, 0, W_v, 1024, 1024, 1024, 0, 0);
  castW_k<<<dim3((1000*1024+255)/256), blk, 0, stream>>>(outwB, 1024, 0, 0, out_w, 1024, 1000, 1024, 0, 0);
  castW_k<<<dim3((24*1024+255)/256), blk, 0, stream>>>(outwB, 1024, 1000, 0, nullptr, 0, 24, 1024, 0, 0);
  castW_k<<<dim3((512*512+255)/256), blk, 0, stream>>>(kvw_B, 512, 0, 0, kv_w, 512, 512, 512, 0, 0);
  castW_k<<<dim3((512*512+255)/256), blk, 0, stream>>>(wkc_B, 512, 0, 0, in_proj_w + 512*512, 512, 512, 512, 0, 0);
  castW_k<<<dim3((512*512+255)/256), blk, 0, stream>>>(wvc_B, 512, 0, 0, in_proj_w + 1024*512, 512, 512, 512, 0, 0);

  vecmat_k<<<dim3(256), blk, 0, stream>>>(W_q, 1024, start_act, nullptr, q0, 1024, 0);
  vecmat_k<<<dim3(256), blk, 0, stream>>>(W_k, 1024, start_act, nullptr, k0, 1024, 0);
  vecmat_k<<<dim3(256), blk, 0, stream>>>(W_v, 1024, start_act, nullptr, v0, 1024, 0);
  vecmat_k<<<dim3(128), blk, 0, stream>>>(in_proj_w, 512, q_b, in_proj_b, bfq, 512, 0);
  vecmat_k<<<dim3(512), blk, 0, stream>>>(syn_w, 1536, out_proj_b, syn_b, bz, 512, 1);

  gemm_tn<false, EpiBF16><<<dim3(8, 8), blk, 0, stream>>>(in_proj_w, 512, qw_B, 512, nullptr, 512, EpiBF16{Wfq, 1024, 0});
  gemm_tn<false, EpiBF16><<<dim3(4, 32), blk, 0, stream>>>(syn_w, 1536, opw_B, 512, nullptr, 512, EpiBF16{Wz, 1536, 1});

  zero_k<<<dim3(98), blk, 0, stream>>>(kvstats, 25088);
  gemm_tn<false, EpiKVpre><<<dim3(4, 196), blk, 0, stream>>>(x, 512, kvw_B, 512, kv_b, 512, EpiKVpre{kvp, kvstats});
  ln_inplace_k<<<dim3(25088), blk, 0, stream>>>(kvp, kvstats, ln_kv_s, ln_kv_b);
  gemm_tn<true, EpiBF16><<<dim3(4, 196), blk, 0, stream>>>(kvp, 512, wkc_B, 512, in_proj_b + 512, 512, EpiBF16{Kc, 512, 0});
  gemm_tn<true, EpiBF16><<<dim3(4, 196), blk, 0, stream>>>(kvp, 512, wvc_B, 512, in_proj_b + 1024, 512, EpiBF16{Vc, 512, 0});

  // kvp is dead from here on; its storage becomes the fresh-per-tick oa ring.
  fill_k<<<dim3(14848), blk, 0, stream>>>(Qbuf, Kbuf, vcur, oaR, st, q0, k0, v0, start_act, strace);

  // ---- the whole 50-tick recurrence in ONE persistent kernel ----
  int nb = 256; // safe fallback (1 block/CU always resident)
  {
    int mb = 0;
    if (hipOccupancyMaxActiveBlocksPerMultiprocessor(&mb, reinterpret_cast<const void*>(tick_all_k), 256, 0) == hipSuccess && mb >= 1){
      int dev = 0; hipGetDevice(&dev);
      int ncu = 0;
      if (hipDeviceGetAttribute(&ncu, hipDeviceAttributeMultiprocessorCount, dev) != hipSuccess || ncu <= 0) ncu = 256;
      long cap = (long)mb * (long)ncu;
      nb = (int)(cap < 512 ? cap : 512);
    }
  }
  tick_all_k<<<dim3(nb), blk, 0, stream>>>(Wfq, bfq, Kc, Vc, Wz, bz, ubuf, stats,
      syn_ln_s, syn_ln_b, st, nlm_w1, nlm_b1, nlm_w2, nlm_b2, Wqkv,
      Qbuf, Kbuf, vcur, S, S_bf, SyncO, oaR, bar);

  // ---- epilogue: deferred output head ----
  gemm_tn<true, EpiPred><<<dim3(8, 50), blk, 0, stream>>>(SyncO, 1024, outwB, 1024, out_b, 1024, EpiPred{out});
  cert_k<<<dim3(50, 64), blk, 0, stream>>>(out, out + 3200000);
  copy_sync_k<<<dim3(256), blk, 0, stream>>>(S, out + 3206400);
}

// Round 6
// 6631.863 us; speedup vs baseline: 1.4556x; 1.1045x over previous
//
#include <hip/hip_runtime.h>
#include <hip/hip_bf16.h>

typedef __attribute__((ext_vector_type(8))) short short8v;
typedef __attribute__((ext_vector_type(4))) float f32x4;
typedef __attribute__((ext_vector_type(4))) float float4v;

#define DEV __device__ __forceinline__

DEV short f2bfs(float x){
  union { float f; unsigned u; } v; v.f = x;
  unsigned r = (v.u + 0x7FFFu + ((v.u >> 16) & 1u)) >> 16;
  return (short)(unsigned short)r;
}
DEV float bfs2f(short s){
  union { unsigned u; float f; } v; v.u = ((unsigned)(unsigned short)s) << 16;
  return v.f;
}
DEV float sigm(float x){ return 1.f / (1.f + __expf(-x)); }
DEV int zmap(int j){ int g = (j >= 1024) ? 1 : 0; int i = j - (g << 10); return (i & 15) + ((i >> 4) << 5) + (g << 4); }

// Agent-scope (L2-bypassing) loads: only for reused-address cross-XCD state.
DEV float aldf(const void* p){ return __hip_atomic_load((const float*)p, __ATOMIC_RELAXED, __HIP_MEMORY_SCOPE_AGENT); }

// ================= device-scope grid barrier (release-writeback, no invalidate) =================
DEV void gbar(unsigned* bar, int nb){
  __syncthreads();
  if (threadIdx.x == 0){
    __builtin_amdgcn_fence(__ATOMIC_RELEASE, "agent");
    unsigned* gen = bar + 128;
    unsigned g = __hip_atomic_load(gen, __ATOMIC_RELAXED, __HIP_MEMORY_SCOPE_AGENT);
    int lane = blockIdx.x & 7;
    __hip_atomic_fetch_add(bar + lane*16, 1u, __ATOMIC_RELAXED, __HIP_MEMORY_SCOPE_AGENT);
    if (blockIdx.x == 0){
      unsigned sum;
      do {
        sum = 0;
#pragma unroll
        for (int i = 0; i < 8; i++) sum += __hip_atomic_load(bar + i*16, __ATOMIC_RELAXED, __HIP_MEMORY_SCOPE_AGENT);
      } while (sum < (unsigned)nb);
#pragma unroll
      for (int i = 0; i < 8; i++) __hip_atomic_store(bar + i*16, 0u, __ATOMIC_RELAXED, __HIP_MEMORY_SCOPE_AGENT);
      __hip_atomic_store(gen, g + 1u, __ATOMIC_RELEASE, __HIP_MEMORY_SCOPE_AGENT);
    } else {
      while (__hip_atomic_load(gen, __ATOMIC_RELAXED, __HIP_MEMORY_SCOPE_AGENT) == g)
        __builtin_amdgcn_s_sleep(1);
    }
  }
  __syncthreads();
}

// ================= tick phases =================

// Phase 1: Qh projection + cross-attention for (b, h). h = XCD id -> Wfq slice local.
// Sslot: S ring slot (fresh address, plain). Kc/Vc: nontemporal stream.
DEV void phase_qhcross(int b, int h, const short* __restrict__ Wfq, const float* __restrict__ bfq,
    const short* __restrict__ Kc, const short* __restrict__ Vc, const short* __restrict__ Sslot,
    short* __restrict__ oaC, float* __restrict__ stats, float* smf, int tid, int zero_stats)
{
  float* Srow = smf;          // 1024
  float* qs   = smf + 1024;   // 64
  float* wsm  = smf + 1088;   // 256
  float* red  = smf + 1344;   // 256
  __syncthreads();
  // V prefetch into registers (nontemporal) — overlaps with K fetch + scores.
  int cc = tid >> 6, dd = tid & 63;
  unsigned short vv[49];
  {
    const unsigned short* vp = (const unsigned short*)Vc + ((size_t)(b*196 + cc)*512 + h*64 + dd);
#pragma unroll
    for (int i = 0; i < 49; i++)
      vv[i] = __builtin_nontemporal_load(vp + (size_t)i*2048);
  }
  {
    const int* sp = (const int*)Sslot + b*512;
    int v0 = sp[tid], v1 = sp[tid + 256];
    Srow[tid*2]           = bfs2f((short)(v0 & 0xffff));
    Srow[tid*2 + 1]       = bfs2f((short)(((unsigned)v0) >> 16));
    Srow[512 + tid*2]     = bfs2f((short)(v1 & 0xffff));
    Srow[512 + tid*2 + 1] = bfs2f((short)(((unsigned)v1) >> 16));
  }
  if (zero_stats && tid < 128) stats[tid] = 0.f;
  __syncthreads();
  {
    int d = tid & 63, c = tid >> 6;
    const short* wp = Wfq + (size_t)(h*64 + d)*1024 + c*256;
    const float* srp = Srow + c*256;
    float acc = 0.f;
#pragma unroll 4
    for (int i = 0; i < 256; i += 8){
      short8v wv = *(const short8v*)(wp + i);
#pragma unroll
      for (int j = 0; j < 8; j++) acc += bfs2f(wv[j]) * srp[i + j];
    }
    red[tid] = acc;
  }
  __syncthreads();
  if (tid < 64) qs[tid] = bfq[h*64 + tid] + red[tid] + red[tid+64] + red[tid+128] + red[tid+192];
  __syncthreads();
  float sv = -1e30f;
  if (tid < 196){
    const short8v* kp = (const short8v*)(Kc + ((size_t)(b*196 + tid)*512 + h*64));
    float acc = 0.f;
#pragma unroll
    for (int j = 0; j < 8; j++){
      short8v kv8 = __builtin_nontemporal_load(kp + j);
#pragma unroll
      for (int u8 = 0; u8 < 8; u8++) acc += bfs2f(kv8[u8]) * qs[j*8 + u8];
    }
    sv = acc * 0.125f;
  }
  red[tid] = sv; __syncthreads();
  for (int s = 128; s > 0; s >>= 1){ if (tid < s) red[tid] = fmaxf(red[tid], red[tid+s]); __syncthreads(); }
  float M = red[0]; __syncthreads();
  float e = (tid < 196) ? __expf(sv - M) : 0.f;
  wsm[tid] = e; red[tid] = e; __syncthreads();
  for (int s = 128; s > 0; s >>= 1){ if (tid < s) red[tid] += red[tid+s]; __syncthreads(); }
  float Z = red[0]; __syncthreads();
  float acc = 0.f;
#pragma unroll
  for (int i = 0; i < 49; i++) acc += wsm[cc + 4*i] * bfs2f((short)vv[i]);
  red[tid] = acc; __syncthreads();
  if (tid < 64){
    float o = (red[tid] + red[tid+64] + red[tid+128] + red[tid+192]) / Z;
    oaC[(size_t)b*1536 + h*64 + tid] = f2bfs(o);
  }
  __syncthreads();
}

// Phase 2: GLU GEMM strip (32 cols of N=2048), 4-wave K-split over K=1536.
DEV void phase_glu(int n0, const short* __restrict__ Wz, const float* __restrict__ bz,
    const short* __restrict__ oaC, float* __restrict__ ubuf, float* __restrict__ stats,
    float* smf, int tid)
{
  float* part   = smf;
  float* statsl = smf + 8192;
  __syncthreads();
  if (tid < 128) statsl[tid] = 0.f;
  int w = tid >> 6, l15 = tid & 15, l4 = (tid >> 4) & 3;
  f32x4 acc[4][2];
#pragma unroll
  for (int mi = 0; mi < 4; mi++)
#pragma unroll
    for (int ni = 0; ni < 2; ni++) acc[mi][ni] = (f32x4){0.f,0.f,0.f,0.f};
#pragma unroll 2
  for (int it = 0; it < 12; it++){
    int ks = w*384 + it*32 + l4*8;
    short8v a4[4], bb[2];
#pragma unroll
    for (int mi = 0; mi < 4; mi++)
      a4[mi] = *(const short8v*)(oaC + (size_t)(mi*16 + l15)*1536 + ks);
#pragma unroll
    for (int ni = 0; ni < 2; ni++)
      bb[ni] = *(const short8v*)(Wz + (size_t)(n0 + ni*16 + l15)*1536 + ks);
#pragma unroll
    for (int mi = 0; mi < 4; mi++)
#pragma unroll
      for (int ni = 0; ni < 2; ni++)
        acc[mi][ni] = __builtin_amdgcn_mfma_f32_16x16x32_bf16(a4[mi], bb[ni], acc[mi][ni], 0, 0, 0);
  }
#pragma unroll
  for (int mi = 0; mi < 4; mi++)
#pragma unroll
    for (int ni = 0; ni < 2; ni++)
#pragma unroll
      for (int r = 0; r < 4; r++)
        part[w*2048 + (mi*16 + l4*4 + r)*32 + ni*16 + l15] = acc[mi][ni][r];
  __syncthreads();
  int m = tid >> 2;
  float s1 = 0.f, s2 = 0.f;
#pragma unroll
  for (int e = 0; e < 4; e++){
    int j = ((tid & 3) << 2) + e;
    float a = part[m*32 + j] + part[2048 + m*32 + j] + part[4096 + m*32 + j] + part[6144 + m*32 + j] + bz[n0 + j];
    float g = part[m*32 + 16 + j] + part[2048 + m*32 + 16 + j] + part[4096 + m*32 + 16 + j] + part[6144 + m*32 + 16 + j] + bz[n0 + 16 + j];
    float uv = a * sigm(g);
    ubuf[(size_t)m*1024 + (n0 >> 1) + j] = uv;
    s1 += uv; s2 += uv*uv;
  }
  atomicAdd(&statsl[m], s1); atomicAdd(&statsl[64 + m], s2);
  __syncthreads();
  if (tid < 64){ atomicAdd(&stats[tid], statsl[tid]); atomicAdd(&stats[64 + tid], statsl[64 + tid]); }
  __syncthreads();
}

// Phase 3: LN + trace append + per-neuron NLM for (x = d-slice, y = b-group).
// x is XCD-local -> w1/w2/st slices stay in this XCD's L2.
DEV void phase_nlm(int x, int y, const float* __restrict__ ubuf, const float* __restrict__ stats,
    const float* __restrict__ g_s, const float* __restrict__ g_b, float* __restrict__ st,
    const short* __restrict__ w1, const float* __restrict__ b1,
    const short* __restrict__ w2, const float* __restrict__ b2,
    short* __restrict__ oaN, int t, float* smf, int tid)
{
  float* pl = smf; // 4096
  int d_i = tid & 15, b_i = (tid >> 4) & 7, half = tid >> 7;
  int d = x*16 + d_i, b = y*8 + b_i;
  float mu = aldf(stats + b) * (1.f/1024.f);
  float var = aldf(stats + 64 + b) * (1.f/1024.f) - mu*mu;
  float rs = rsqrtf(var + 1e-5f);
  float uv = aldf(ubuf + b*1024 + d);
  float state = (uv - mu)*rs*g_s[d] + g_b[d];
  int slot = t % 25;
  if (half == 0) st[(size_t)slot*65536 + b*1024 + d] = state;
  float pre[16];
#pragma unroll
  for (int hh = 0; hh < 16; hh++) pre[hh] = b1[d*32 + half*16 + hh];
  int p0 = (t + 1) % 25;
#pragma unroll 5
  for (int m = 0; m < 25; m++){
    int p = p0 + m; if (p >= 25) p -= 25;
    float sm = (p == slot) ? state : st[(size_t)p*65536 + b*1024 + d];
#pragma unroll
    for (int hh = 0; hh < 16; hh++) pre[hh] += sm * bfs2f(w1[(size_t)(m*32 + half*16 + hh)*1024 + d]);
  }
  __syncthreads();
#pragma unroll
  for (int hh = 0; hh < 16; hh++) pl[((half*8 + b_i)*16 + hh)*16 + d_i] = pre[hh];
  __syncthreads();
  if (half == 0){
    float p2a = b2[d*2 + 0], p2g = b2[d*2 + 1];
#pragma unroll
    for (int i = 0; i < 16; i++){
      float hv = pl[((b_i)*16 + i)*16 + d_i] * sigm(pl[((8 + b_i)*16 + i)*16 + d_i]);
      p2a += hv * bfs2f(w2[(size_t)(i*2 + 0)*1024 + d]);
      p2g += hv * bfs2f(w2[(size_t)(i*2 + 1)*1024 + d]);
    }
    float act = p2a * sigm(p2g);
    oaN[(size_t)b*1536 + 512 + d] = f2bfs(act);
  }
  __syncthreads();
}

// Phase 4: QKV GEMM strip. Writes append-only slot-major rings (plain stores).
DEV void phase_qkv(int n0, const short* __restrict__ Wqkv, const short* __restrict__ act_bf,
    short* __restrict__ Qslot, short* __restrict__ Kslot, float* __restrict__ vc,
    float* smf, int tid)
{
  float* part = smf;
  __syncthreads();
  int w = tid >> 6, l15 = tid & 15, l4 = (tid >> 4) & 3;
  f32x4 acc[4][2];
#pragma unroll
  for (int mi = 0; mi < 4; mi++)
#pragma unroll
    for (int ni = 0; ni < 2; ni++) acc[mi][ni] = (f32x4){0.f,0.f,0.f,0.f};
#pragma unroll 2
  for (int it = 0; it < 8; it++){
    int ks = w*256 + it*32 + l4*8;
    short8v a4[4], bb[2];
#pragma unroll
    for (int mi = 0; mi < 4; mi++)
      a4[mi] = *(const short8v*)(act_bf + (size_t)(mi*16 + l15)*1536 + ks);
#pragma unroll
    for (int ni = 0; ni < 2; ni++)
      bb[ni] = *(const short8v*)(Wqkv + (size_t)(n0 + ni*16 + l15)*1024 + ks);
#pragma unroll
    for (int mi = 0; mi < 4; mi++)
#pragma unroll
      for (int ni = 0; ni < 2; ni++)
        acc[mi][ni] = __builtin_amdgcn_mfma_f32_16x16x32_bf16(a4[mi], bb[ni], acc[mi][ni], 0, 0, 0);
  }
#pragma unroll
  for (int mi = 0; mi < 4; mi++)
#pragma unroll
    for (int ni = 0; ni < 2; ni++)
#pragma unroll
      for (int r = 0; r < 4; r++)
        part[w*2048 + (mi*16 + l4*4 + r)*32 + ni*16 + l15] = acc[mi][ni][r];
  __syncthreads();
  int m = tid >> 2;
#pragma unroll
  for (int e = 0; e < 8; e++){
    int nl = ((tid & 3) << 3) + e;
    float v = part[m*32 + nl] + part[2048 + m*32 + nl] + part[4096 + m*32 + nl] + part[6144 + m*32 + nl];
    int n = n0 + nl;
    if (n < 1024)      Qslot[(size_t)m*1024 + n] = f2bfs(v);
    else if (n < 2048) Kslot[(size_t)m*1024 + (n-1024)] = f2bfs(v);
    else               vc[(size_t)m*1024 + (n-2048)] = v;
  }
  __syncthreads();
}

// Phase 5: neuron-sync attention for (b, h). Reads slot-major rings (plain, L2-hot window).
DEV void phase_sync(int b, int h, int t, const short* __restrict__ Qn, const short* __restrict__ Kn,
    const float* __restrict__ vcur, float* __restrict__ S, short* __restrict__ SslotN,
    short* __restrict__ SyncO, float* smf, int tid)
{
  short* qt = (short*)smf;     // 4096 shorts (8 KB), rows [d=128][32 slot-chunk-swizzled]
  short* kt = qt + 4096;
  __syncthreads();
  const short* Qb = Qn + (size_t)(t+1)*65536 + b*1024 + h*128;
  const short* Kb = Kn + (size_t)(t+1)*65536 + b*1024 + h*128;
#pragma unroll
  for (int pass = 0; pass < 8; pass++){
    int ch = tid + pass*256;
    int m = ch >> 6, ii = ch & 63, d = ii << 1;
    int qv = 0, kv = 0;
    if (m < 25){
      qv = *(const int*)(Qb + (size_t)m*65536 + d);
      kv = *(const int*)(Kb + (size_t)m*65536 + d);
    }
    int c = m >> 3, pos = m & 7;
    int cs = c ^ ((d >> 1) & 3);   // (d even; d+1 has same d>>1)
    qt[d*32 + cs*8 + pos]       = (short)(qv & 0xffff);
    qt[(d+1)*32 + cs*8 + pos]   = (short)(((unsigned)qv) >> 16);
    kt[d*32 + cs*8 + pos]       = (short)(kv & 0xffff);
    kt[(d+1)*32 + cs*8 + pos]   = (short)(((unsigned)kv) >> 16);
  }
  __syncthreads();
  const short8v* qlds = (const short8v*)qt;
  const short8v* klds = (const short8v*)kt;
  int w = tid >> 6, l15 = tid & 15, l4 = (tid >> 4) & 3;
  short8v af[2], bfr[8];
#pragma unroll
  for (int mi2 = 0; mi2 < 2; mi2++){
    int d = (2*w + mi2)*16 + l15;
    af[mi2] = qlds[d*4 + (l4 ^ ((d >> 1) & 3))];
  }
#pragma unroll
  for (int ni = 0; ni < 8; ni++){
    int e = ni*16 + l15;
    bfr[ni] = klds[e*4 + (l4 ^ ((e >> 1) & 3))];
  }
  f32x4 acc[2][8];
#pragma unroll
  for (int mi2 = 0; mi2 < 2; mi2++)
#pragma unroll
    for (int ni = 0; ni < 8; ni++)
      acc[mi2][ni] = (f32x4){0.f,0.f,0.f,0.f};
#pragma unroll
  for (int mi2 = 0; mi2 < 2; mi2++)
#pragma unroll
    for (int ni = 0; ni < 8; ni++)
      acc[mi2][ni] = __builtin_amdgcn_mfma_f32_16x16x32_bf16(af[mi2], bfr[ni], acc[mi2][ni], 0, 0, 0);
  float Vv[8];
#pragma unroll
  for (int ni = 0; ni < 8; ni++) Vv[ni] = aldf(vcur + b*1024 + h*128 + ni*16 + l15);
  const float scale = 0.08838834764831845f; // 1/sqrt(128)
#pragma unroll
  for (int mi2 = 0; mi2 < 2; mi2++)
#pragma unroll
    for (int r = 0; r < 4; r++){
      float sv[8]; float mx = -1e30f;
#pragma unroll
      for (int ni = 0; ni < 8; ni++){ sv[ni] = acc[mi2][ni][r]*scale; mx = fmaxf(mx, sv[ni]); }
#pragma unroll
      for (int off = 1; off < 16; off <<= 1) mx = fmaxf(mx, __shfl_xor(mx, off));
      float den = 0.f, num = 0.f;
#pragma unroll
      for (int ni = 0; ni < 8; ni++){ float p = __expf(sv[ni] - mx); den += p; num += p*Vv[ni]; }
#pragma unroll
      for (int off = 1; off < 16; off <<= 1){ den += __shfl_xor(den, off); num += __shfl_xor(num, off); }
      if (l15 == 0){
        int d = (2*w + mi2)*16 + l4*4 + r;
        float att = num / den;
        int oi = b*1024 + d*8 + h;
        S[oi] = att;
        SslotN[oi] = f2bfs(att);
        if (t >= 0) SyncO[((size_t)b*50 + t)*1024 + d*8 + h] = f2bfs(att);
      }
    }
  __syncthreads();
}

// ================= the persistent 50-tick kernel =================
__global__ __launch_bounds__(256, 2) void tick_all_k(
    const short* __restrict__ Wfq, const float* __restrict__ bfq,
    const short* __restrict__ Kc, const short* __restrict__ Vc,
    const short* __restrict__ Wz, const float* __restrict__ bz,
    float* __restrict__ ubuf, float* __restrict__ stats,
    const float* __restrict__ g_s, const float* __restrict__ g_b,
    float* __restrict__ st,
    const short* __restrict__ w1, const float* __restrict__ b1,
    const short* __restrict__ w2, const float* __restrict__ b2,
    const short* __restrict__ Wqkv,
    short* __restrict__ Qn, short* __restrict__ Kn, float* __restrict__ vcur,
    float* __restrict__ S, short* __restrict__ S_bfR, short* __restrict__ SyncO,
    short* __restrict__ oaR, unsigned* bar)
{
  __shared__ float smf[8320];
  const int tid = threadIdx.x;
  const int bid = blockIdx.x;
  const int nb  = gridDim.x;
  const int k   = bid & 7;        // XCD id (bid round-robins XCDs)
  const int j0  = bid >> 3;
  const int js  = nb >> 3;        // blocks per XCD

  // initial sync (t=-1): window = ring slots 0..24 -> S ring slot 0
  for (int j = j0; j < 64; j += js)
    phase_sync(k*8 + (j & 7), j >> 3, -1, Qn, Kn, vcur, S, S_bfR, SyncO, smf, tid);
  gbar(bar, nb);

#pragma unroll 1
  for (int t = 0; t < 50; t++){
    const short* Sslot = S_bfR + (size_t)t * 65536;
    short* SslotN      = S_bfR + (size_t)(t+1) * 65536;
    short* oaC = oaR + (size_t)t * 98304;
    short* oaN = oaR + (size_t)(t+1) * 98304;
    for (int j = j0; j < 64; j += js)
      phase_qhcross(j, k, Wfq, bfq, Kc, Vc, Sslot, oaC, stats, smf, tid, (bid == 0 && j == j0));
    gbar(bar, nb);
    for (int j = j0; j < 8; j += js)
      phase_glu((k*8 + j)*32, Wz, bz, oaC, ubuf, stats, smf, tid);
    gbar(bar, nb);
    for (int j = j0; j < 64; j += js)
      phase_nlm(k*8 + (j & 7), j >> 3, ubuf, stats, g_s, g_b, st, w1, b1, w2, b2, oaN, t, smf, tid);
    gbar(bar, nb);
    for (int j = j0; j < 12; j += js){
      int n0 = ((j >> 2)*32 + k*4 + (j & 3)) * 32;
      phase_qkv(n0, Wqkv, oaN + 512, Qn + (size_t)(25+t)*65536, Kn + (size_t)(25+t)*65536, vcur, smf, tid);
    }
    gbar(bar, nb);
    for (int j = j0; j < 64; j += js)
      phase_sync(k*8 + (j & 7), j >> 3, t, Qn, Kn, vcur, S, SslotN, SyncO, smf, tid);
    gbar(bar, nb);
  }
}

// ================= prologue / epilogue =================
struct EpiBF16 {
  short* C; int ldc; int domap;
  DEV void op(const f32x4 (&acc)[4][2], int m0, int n0, int l15, int l4, const float* bias) const {
#pragma unroll
    for (int mi = 0; mi < 4; mi++)
#pragma unroll
      for (int ni = 0; ni < 2; ni++){
        int n = n0 + ni*16 + l15;
        float bb = bias ? bias[n] : 0.f;
#pragma unroll
        for (int r = 0; r < 4; r++){
          int m = m0 + mi*16 + l4*4 + r;
          int mr = domap ? zmap(m) : m;
          C[(size_t)mr*ldc + n] = f2bfs(acc[mi][ni][r] + bb);
        }
      }
  }
};

struct EpiPred {
  float* outp;
  DEV void op(const f32x4 (&acc)[4][2], int m0, int n0, int l15, int l4, const float* bias) const {
#pragma unroll
    for (int mi = 0; mi < 4; mi++)
#pragma unroll
      for (int ni = 0; ni < 2; ni++){
        int n = n0 + ni*16 + l15;
        if (n >= 1000) continue;
        float bb = bias[n];
#pragma unroll
        for (int r = 0; r < 4; r++){
          int m = m0 + mi*16 + l4*4 + r;
          int b = m / 50, tt = m - b*50;
          outp[(size_t)b*50000 + (size_t)n*50 + tt] = acc[mi][ni][r] + bb;
        }
      }
  }
};

struct EpiKVpre {
  short* C; float* stats;
  DEV void op(const f32x4 (&acc)[4][2], int m0, int n0, int l15, int l4, const float* bias) const {
    float b0 = bias[n0 + l15], b1 = bias[n0 + 16 + l15];
#pragma unroll
    for (int mi = 0; mi < 4; mi++)
#pragma unroll
      for (int r = 0; r < 4; r++){
        int m = m0 + mi*16 + l4*4 + r;
        float v0 = acc[mi][0][r] + b0;
        float v1 = acc[mi][1][r] + b1;
        C[(size_t)m*512 + n0 + l15]      = f2bfs(v0);
        C[(size_t)m*512 + n0 + 16 + l15] = f2bfs(v1);
        float s = v0 + v1, s2 = v0*v0 + v1*v1;
#pragma unroll
        for (int off = 1; off < 16; off <<= 1){ s += __shfl_xor(s, off); s2 += __shfl_xor(s2, off); }
        if (l15 == 0){ atomicAdd(&stats[m*2], s); atomicAdd(&stats[m*2 + 1], s2); }
      }
  }
};

template<bool ABF16, typename EPI>
__global__ __launch_bounds__(256) void gemm_tn(const void* __restrict__ Aptr, int lda,
    const short* __restrict__ Bw, int ldb, const float* __restrict__ bias,
    int K, EPI epi)
{
  int tid = threadIdx.x;
  const int w = tid >> 6, l15 = tid & 15, l4 = (tid >> 4) & 3;
  const int m0 = blockIdx.y * 64;
  const int n0 = blockIdx.x * 128 + w * 32;
  f32x4 acc[4][2];
#pragma unroll
  for (int mi = 0; mi < 4; mi++)
#pragma unroll
    for (int ni = 0; ni < 2; ni++)
      acc[mi][ni] = (f32x4){0.f, 0.f, 0.f, 0.f};
#pragma unroll 4
  for (int kk = 0; kk < K; kk += 32){
    const int ks = kk + l4*8;
    short8v a[4], bfr[2];
#pragma unroll
    for (int mi = 0; mi < 4; mi++){
      const size_t row = (size_t)(m0 + mi*16 + l15);
      if (ABF16){
        a[mi] = *(const short8v*)((const short*)Aptr + row*lda + ks);
      } else {
        const float* ap = (const float*)Aptr + row*lda + ks;
        float4v f0 = *(const float4v*)ap;
        float4v f1 = *(const float4v*)(ap + 4);
        short8v tt;
        tt[0]=f2bfs(f0[0]); tt[1]=f2bfs(f0[1]); tt[2]=f2bfs(f0[2]); tt[3]=f2bfs(f0[3]);
        tt[4]=f2bfs(f1[0]); tt[5]=f2bfs(f1[1]); tt[6]=f2bfs(f1[2]); tt[7]=f2bfs(f1[3]);
        a[mi] = tt;
      }
    }
#pragma unroll
    for (int ni = 0; ni < 2; ni++)
      bfr[ni] = *(const short8v*)(Bw + (size_t)(n0 + ni*16 + l15)*ldb + ks);
#pragma unroll
    for (int mi = 0; mi < 4; mi++)
#pragma unroll
      for (int ni = 0; ni < 2; ni++)
        acc[mi][ni] = __builtin_amdgcn_mfma_f32_16x16x32_bf16(a[mi], bfr[ni], acc[mi][ni], 0, 0, 0);
  }
  epi.op(acc, m0, n0, l15, l4, bias);
}

__global__ __launch_bounds__(256) void vecmat_k(const float* __restrict__ W, int ldw,
    const float* __restrict__ v, const float* __restrict__ add, float* __restrict__ out, int K, int domap)
{
  int w = threadIdx.x >> 6, l = threadIdx.x & 63;
  int n = blockIdx.x*4 + w;
  float s = 0.f;
  for (int k = l; k < K; k += 64) s += W[(size_t)n*ldw + k]*v[k];
#pragma unroll
  for (int off = 32; off; off >>= 1) s += __shfl_xor(s, off);
  if (l == 0){ float o = s + (add ? add[n] : 0.f); out[domap ? zmap(n) : n] = o; }
}

__global__ void castW_k(short* dst, int dld, int drow0, int dcol0,
    const float* src, int sld, int N, int K, int transp, int domap)
{
  size_t idx = (size_t)blockIdx.x*256 + threadIdx.x;
  size_t tot = (size_t)N*K;
  if (idx >= tot) return;
  int n = idx / K, k = idx - (size_t)n*K;
  float vv = 0.f;
  if (src) vv = transp ? src[(size_t)k*sld + n] : src[(size_t)n*sld + k];
  int r = drow0 + (domap ? zmap(n) : n);
  dst[(size_t)r*dld + dcol0 + k] = f2bfs(vv);
}

__global__ void zero_k(float* p, int n){
  int i = blockIdx.x*256 + threadIdx.x;
  if (i < n) p[i] = 0.f;
}

__global__ void ln_inplace_k(short* kvp, const float* __restrict__ stats,
    const float* __restrict__ s, const float* __restrict__ bb)
{
  size_t i = (size_t)blockIdx.x*256 + threadIdx.x;
  int row = i >> 9, c = i & 511;
  float mu = stats[row*2] * (1.f/512.f);
  float var = stats[row*2 + 1] * (1.f/512.f) - mu*mu;
  float v = bfs2f(kvp[i]);
  kvp[i] = f2bfs((v - mu)*rsqrtf(var + 1e-5f)*s[c] + bb[c]);
}

__global__ void fill_k(short* Qn, short* Kn, float* vcur, short* oaR,
    float* st, const float* q0, const float* k0, const float* v0,
    const float* start, const float* strace)
{
  size_t i = (size_t)blockIdx.x*256 + threadIdx.x;
  const size_t H = 25u*65536u;
  if (i < H){
    int d = (int)(i & 1023);
    Qn[i] = f2bfs(q0[d]);
    Kn[i] = f2bfs(k0[d]);
    return;
  }
  i -= H;
  if (i < 65536){
    int d = (int)(i & 1023); int b = (int)(i >> 10);
    vcur[i] = v0[d];
    oaR[(size_t)b*1536 + 512 + d] = f2bfs(start[d]);
    return;
  }
  i -= 65536;
  if (i < H){
    int p = (int)(i >> 16), d = (int)(i & 1023);
    st[i] = strace[d*25 + p];  // st: [25 slots][b*1024+d]
  }
}

__global__ __launch_bounds__(256) void cert_k(const float* __restrict__ preds, float* __restrict__ cert)
{
  int t = blockIdx.x, b = blockIdx.y, tid = threadIdx.x;
  __shared__ float red[256];
  float v[4]; float mx = -1e30f;
#pragma unroll
  for (int i = 0; i < 4; i++){
    int o = tid + i*256;
    v[i] = (o < 1000) ? preds[(size_t)b*50000 + (size_t)o*50 + t] : -1e30f;
    mx = fmaxf(mx, v[i]);
  }
  red[tid] = mx; __syncthreads();
  for (int s = 128; s; s >>= 1){ if (tid < s) red[tid] = fmaxf(red[tid], red[tid + s]); __syncthreads(); }
  float M = red[0]; __syncthreads();
  float z = 0.f, wsum = 0.f;
#pragma unroll
  for (int i = 0; i < 4; i++){
    int o = tid + i*256;
    if (o < 1000){ float p = v[i] - M; float e = __expf(p); z += e; wsum += e*p; }
  }
  red[tid] = z; __syncthreads();
  for (int s = 128; s; s >>= 1){ if (tid < s) red[tid] += red[tid + s]; __syncthreads(); }
  float Z = red[0]; __syncthreads();
  red[tid] = wsum; __syncthreads();
  for (int s = 128; s; s >>= 1){ if (tid < s) red[tid] += red[tid + s]; __syncthreads(); }
  float Wm = red[0];
  if (tid == 0){
    float ne = (__logf(Z) - Wm/Z) * 0.14476482730108392f;
    cert[b*100 + t] = ne;
    cert[b*100 + 50 + t] = 1.f - ne;
  }
}

__global__ void copy_sync_k(const float* __restrict__ S, float* __restrict__ out){
  int i = blockIdx.x*256 + threadIdx.x;
  out[i] = S[i];
}

// ============================== host ==============================
extern "C" void kernel_launch(void* const* d_in, const int* in_sizes, int n_in,
                              void* d_out, int out_size, void* d_ws, size_t ws_size,
                              hipStream_t stream)
{
  const float* x        = (const float*)d_in[0];
  const float* kv_w     = (const float*)d_in[1];
  const float* kv_b     = (const float*)d_in[2];
  const float* ln_kv_s  = (const float*)d_in[3];
  const float* ln_kv_b  = (const float*)d_in[4];
  const float* q_w      = (const float*)d_in[5];
  const float* q_b      = (const float*)d_in[6];
  const float* in_proj_w= (const float*)d_in[7];
  const float* in_proj_b= (const float*)d_in[8];
  const float* out_proj_w=(const float*)d_in[9];
  const float* out_proj_b=(const float*)d_in[10];
  const float* W_q      = (const float*)d_in[11];
  const float* W_k      = (const float*)d_in[12];
  const float* W_v      = (const float*)d_in[13];
  const float* syn_w    = (const float*)d_in[14];
  const float* syn_b    = (const float*)d_in[15];
  const float* syn_ln_s = (const float*)d_in[16];
  const float* syn_ln_b = (const float*)d_in[17];
  const float* nlm_w1   = (const float*)d_in[18];
  const float* nlm_b1   = (const float*)d_in[19];
  const float* nlm_w2   = (const float*)d_in[20];
  const float* nlm_b2   = (const float*)d_in[21];
  const float* start_act= (const float*)d_in[22];
  const float* strace   = (const float*)d_in[23];
  const float* out_w    = (const float*)d_in[24];
  const float* out_b    = (const float*)d_in[25];
  float* out = (float*)d_out;

  char* ws = (char*)d_ws;
  size_t off = 0;
  auto alloc = [&](size_t bytes)->char*{ char* p = ws + off; off = (off + bytes + 255) & ~(size_t)255; return p; };

  short* qw_B   = (short*)alloc((size_t)1024*512*2);
  short* opw_B  = (short*)alloc((size_t)512*512*2);
  short* Wfq    = (short*)alloc((size_t)512*1024*2);
  float* bfq    = (float*)alloc(512*4);
  short* Wz     = (short*)alloc((size_t)2048*1536*2);
  float* bz     = (float*)alloc(2048*4);
  short* Wqkv   = (short*)alloc((size_t)3072*1024*2);
  short* outwB  = (short*)alloc((size_t)1024*1024*2);
  short* kvw_B  = (short*)alloc((size_t)512*512*2);
  short* wkc_B  = (short*)alloc((size_t)512*512*2);
  short* wvc_B  = (short*)alloc((size_t)512*512*2);
  short* kvp    = (short*)alloc((size_t)12544*512*2);   // aliased as oa ring later
  float* kvstats= (float*)alloc((size_t)25088*4);
  short* Kc     = (short*)alloc((size_t)12544*512*2);
  short* Vc     = (short*)alloc((size_t)12544*512*2);
  short* Qn     = (short*)alloc((size_t)75*65536*2);    // append-only Q-proj ring
  short* Kn     = (short*)alloc((size_t)75*65536*2);
  float* vcur   = (float*)alloc((size_t)65536*4);
  float* S      = (float*)alloc((size_t)65536*4);
  short* S_bfR  = (short*)alloc((size_t)51*65536*2);    // S ring (bf16)
  short* SyncO  = (short*)alloc((size_t)64*50*1024*2);
  float* ubuf   = (float*)alloc((size_t)65536*4);
  float* stats  = (float*)alloc(128*4);
  float* st     = (float*)alloc((size_t)1638400*4);
  short* w1b    = (short*)alloc((size_t)800*1024*2);
  short* w2b    = (short*)alloc((size_t)32*1024*2);
  float* q0     = (float*)alloc(1024*4);
  float* k0     = (float*)alloc(1024*4);
  float* v0     = (float*)alloc(1024*4);
  unsigned* bar = (unsigned*)alloc(1024);
  short* oaR    = kvp; // 51*98304 shorts = 10.0 MB <= kvp 12.8 MB (dead after prologue)
  (void)ws_size; (void)in_sizes; (void)n_in; (void)out_size;

  dim3 blk(256);

  // ---- prologue ----
  zero_k<<<dim3(1), blk, 0, stream>>>((float*)bar, 256);
  castW_k<<<dim3((1024*512+255)/256), blk, 0, stream>>>(qw_B, 512, 0, 0, q_w, 1024, 1024, 512, 1, 0);
  castW_k<<<dim3((512*512+255)/256), blk, 0, stream>>>(opw_B, 512, 0, 0, out_proj_w, 512, 512, 512, 1, 0);
  castW_k<<<dim3((2048*1024+255)/256), blk, 0, stream>>>(Wz, 1536, 0, 512, syn_w + 512, 1536, 2048, 1024, 0, 1);
  castW_k<<<dim3((1024*1024+255)/256), blk, 0, stream>>>(Wqkv, 1024, 0, 0, W_q, 1024, 1024, 1024, 0, 0);
  castW_k<<<dim3((1024*1024+255)/256), blk, 0, stream>>>(Wqkv, 1024, 1024, 0, W_k, 1024, 1024, 1024, 0, 0);
  castW_k<<<dim3((1024*1024+255)/256), blk, 0, stream>>>(Wqkv, 1024, 2048, 0, W_v, 1024, 1024, 1024, 0, 0);
  castW_k<<<dim3((1000*1024+255)/256), blk, 0, stream>>>(outwB, 1024, 0, 0, out_w, 1024, 1000, 1024, 0, 0);
  castW_k<<<dim3((24*1024+255)/256), blk, 0, stream>>>(outwB, 1024, 1000, 0, nullptr, 0, 24, 1024, 0, 0);
  castW_k<<<dim3((512*512+255)/256), blk, 0, stream>>>(kvw_B, 512, 0, 0, kv_w, 512, 512, 512, 0, 0);
  castW_k<<<dim3((512*512+255)/256), blk, 0, stream>>>(wkc_B, 512, 0, 0, in_proj_w + 512*512, 512, 512, 512, 0, 0);
  castW_k<<<dim3((512*512+255)/256), blk, 0, stream>>>(wvc_B, 512, 0, 0, in_proj_w + 1024*512, 512, 512, 512, 0, 0);
  castW_k<<<dim3((800*1024+255)/256), blk, 0, stream>>>(w1b, 1024, 0, 0, nlm_w1, 1024, 800, 1024, 0, 0);
  castW_k<<<dim3((32*1024+255)/256), blk, 0, stream>>>(w2b, 1024, 0, 0, nlm_w2, 1024, 32, 1024, 0, 0);

  vecmat_k<<<dim3(256), blk, 0, stream>>>(W_q, 1024, start_act, nullptr, q0, 1024, 0);
  vecmat_k<<<dim3(256), blk, 0, stream>>>(W_k, 1024, start_act, nullptr, k0, 1024, 0);
  vecmat_k<<<dim3(256), blk, 0, stream>>>(W_v, 1024, start_act, nullptr, v0, 1024, 0);
  vecmat_k<<<dim3(128), blk, 0, stream>>>(in_proj_w, 512, q_b, in_proj_b, bfq, 512, 0);
  vecmat_k<<<dim3(512), blk, 0, stream>>>(syn_w, 1536, out_proj_b, syn_b, bz, 512, 1);

  gemm_tn<false, EpiBF16><<<dim3(8, 8), blk, 0, stream>>>(in_proj_w, 512, qw_B, 512, nullptr, 512, EpiBF16{Wfq, 1024, 0});
  gemm_tn<false, EpiBF16><<<dim3(4, 32), blk, 0, stream>>>(syn_w, 1536, opw_B, 512, nullptr, 512, EpiBF16{Wz, 1536, 1});

  zero_k<<<dim3(98), blk, 0, stream>>>(kvstats, 25088);
  gemm_tn<false, EpiKVpre><<<dim3(4, 196), blk, 0, stream>>>(x, 512, kvw_B, 512, kv_b, 512, EpiKVpre{kvp, kvstats});
  ln_inplace_k<<<dim3(25088), blk, 0, stream>>>(kvp, kvstats, ln_kv_s, ln_kv_b);
  gemm_tn<true, EpiBF16><<<dim3(4, 196), blk, 0, stream>>>(kvp, 512, wkc_B, 512, in_proj_b + 512, 512, EpiBF16{Kc, 512, 0});
  gemm_tn<true, EpiBF16><<<dim3(4, 196), blk, 0, stream>>>(kvp, 512, wvc_B, 512, in_proj_b + 1024, 512, EpiBF16{Vc, 512, 0});

  // kvp dead; its storage becomes the per-tick oa ring.
  fill_k<<<dim3(13056), blk, 0, stream>>>(Qn, Kn, vcur, oaR, st, q0, k0, v0, start_act, strace);

  // ---- persistent 50-tick recurrence ----
  int nb = 256;
  {
    int mb = 0;
    if (hipOccupancyMaxActiveBlocksPerMultiprocessor(&mb, reinterpret_cast<const void*>(tick_all_k), 256, 0) == hipSuccess && mb >= 1){
      int dev = 0; hipGetDevice(&dev);
      int ncu = 0;
      if (hipDeviceGetAttribute(&ncu, hipDeviceAttributeMultiprocessorCount, dev) != hipSuccess || ncu <= 0) ncu = 256;
      long cap = (long)mb * (long)ncu;
      nb = (int)(cap < 512 ? cap : 512);
    }
  }
  nb &= ~7; if (nb < 8) nb = 8;
  tick_all_k<<<dim3(nb), blk, 0, stream>>>(Wfq, bfq, Kc, Vc, Wz, bz, ubuf, stats,
      syn_ln_s, syn_ln_b, st, w1b, nlm_b1, w2b, nlm_b2, Wqkv,
      Qn, Kn, vcur, S, S_bfR, SyncO, oaR, bar);

  // ---- epilogue ----
  gemm_tn<true, EpiPred><<<dim3(8, 50), blk, 0, stream>>>(SyncO, 1024, outwB, 1024, out_b, 1024, EpiPred{out});
  cert_k<<<dim3(50, 64), blk, 0, stream>>>(out, out + 3200000);
  copy_sync_k<<<dim3(256), blk, 0, stream>>>(S, out + 3206400);
}